// Round 15
// baseline (862.861 us; speedup 1.0000x reference)
//
#include <hip/hip_runtime.h>
#include <math.h>

typedef _Float16 f16;
typedef _Float16 f16x8 __attribute__((ext_vector_type(8)));
typedef float f32x4 __attribute__((ext_vector_type(4)));
typedef float f32x2 __attribute__((ext_vector_type(2)));

#define B_TOTAL 4096
#define T_STEPS 128
#define H 96
#define NB 16               // batch rows per block (one 16-row MFMA m-tile)
#define NTH 768             // 12 waves = 3 waves/SIMD
#define NBLK (B_TOTAL/NB)   // 256 blocks = 1 per CU
#define GUP 97              // gbuf unit stride in cells (pad -> <=2-way conflicts)

__device__ __forceinline__ float sigf(float v){ return 1.f/(1.f+__expf(-v)); }
__device__ __forceinline__ float tanhf_(float v){ float e=__expf(2.f*v); return 1.f-2.f/(e+1.f); }

// LDS-only barrier: no vmcnt(0) drain; orders LDS traffic only (R13-proven).
__device__ __forceinline__ void lds_barrier(){
    __builtin_amdgcn_sched_barrier(0);
    asm volatile("s_waitcnt lgkmcnt(0)" ::: "memory");
    __builtin_amdgcn_s_barrier();
    __builtin_amdgcn_sched_barrier(0);
}

// One LSTM layer per kernel, sequential over T. 12-wave split (R14) with
// instruction-lean data movement (R15):
//  - gbuf packed [row][unit][4] f32: elementwise = 1 ds_read_b128 per cell;
//    MFMA side = 4 ds_write_b64 per lane.
//  - ys store: coalesced dword per store-role thread, sourced by re-reading
//    h(t-1) from buf[cur] (it's already there); incremental pointers.
//  - ys prefetch: incremental pointer, one dword per thread.
template<int F, bool IS_L0, bool HAS_YSOUT, bool WRITE_HN, bool IS_LAST>
__global__ __launch_bounds__(NTH, 1)
void lstm_seq(const float* __restrict__ x,     // IS_L0 input
              f16* __restrict__ ys,            // relay [T][B][H] f16 (in/out)
              const float* __restrict__ Wi, const float* __restrict__ Wh,
              const float* __restrict__ bi, const float* __restrict__ bh,
              float* __restrict__ hn1g,        // WRITE_HN: store; IS_LAST: load
              const float* __restrict__ fc1_w, const float* __restrict__ fc1_b,
              const float* __restrict__ fc2_w, const float* __restrict__ fc2_b,
              const float* __restrict__ fc3_w, const float* __restrict__ fc3_b,
              float* __restrict__ out)
{
    constexpr int  KS   = (F + H + 31)/32;   // 4 (F=24) or 6 (F=96)
    constexpr int  KP   = KS*32;
    constexpr int  KPB  = KP*2;              // bytes per act row
    constexpr bool HAS_LO = IS_L0;           // lo plane only for x (slice 0)
    constexpr int  BUF  = 16*KP;             // halves per buffer

    __shared__ f16 sh[2*BUF];                    // hi act plane, double-buffered
    __shared__ f16 sl[HAS_LO ? 2*BUF : 64];      // lo plane (L0 only)
    __shared__ float gbuf[16*GUP*4];             // [row][unit(pad)][gate] f32
    __shared__ float hsum[IS_LAST ? 16*96 : 16];
    __shared__ float z1[IS_LAST ? 16*16 : 16];
    __shared__ float z2[IS_LAST ? 16*8  : 16];

    const int tid=threadIdx.x, lane=tid&63, w=tid>>6;   // w: 0..11
    const int j15=lane&15, g4=lane>>4;
    const int g  = w>>1;                     // unit group 0..5
    const int q0 = (w&1)*2;                  // gates q0, q0+1
    const int u  = 16*g + j15;               // unit 0..95 (MFMA role)
    const int row0=blockIdx.x*NB;

    // elementwise role: 2 cells per thread
    const int eu  = tid>>3;                  // unit 0..95
    const int er0 = (tid&7)*2;               // rows er0, er0+1

    // ys store/re-read role: row sr, unit pair su (coalesced dword)
    const int sr = tid/48, su = (tid - sr*48)*2;
    const int ysrd_off = sr*KPB + (((F+su)*2) ^ ((sr&7)<<4));   // byte off in buf

    for (int i=tid;i<2*BUF;i+=NTH) sh[i]=(f16)0.f;
    if constexpr (HAS_LO)
        for (int i=tid;i<2*BUF;i+=NTH) sl[i]=(f16)0.f;

    // weight B-frags: lane holds W[j=96*(q0+qq)+u][k=32s+8*g4+e]
    f16x8 Bf[2][KS];
#pragma unroll
    for (int qq=0;qq<2;++qq){
        const int j=96*(q0+qq)+u;
#pragma unroll
        for (int s=0;s<KS;++s){
            f16x8 f;
#pragma unroll
            for (int e=0;e<8;++e){
                int k=32*s+8*g4+e;
                float v=0.f;
                if (k<F)        v=Wi[(size_t)j*F+k];
                else if (k-F<H) v=Wh[(size_t)j*H+(k-F)];
                f[e]=(f16)v;
            }
            Bf[qq][s]=f;
        }
    }
    float bq[2];
#pragma unroll
    for (int qq=0;qq<2;++qq) bq[qq]=bi[96*(q0+qq)+u]+bh[96*(q0+qq)+u];

    float c2[2]={0.f,0.f};

    // incremental global pointers
    unsigned* ysst = nullptr;                // store target (starts at t=0 slot)
    if constexpr (HAS_YSOUT)
        ysst = (unsigned*)(ys + (size_t)(row0+sr)*H + su);

    const int yi=tid*2, yr=yi/H, yk=yi-yr*H;     // prefetch role: 1 dword each
    const f16* yld = (!IS_L0) ? ys + (size_t)B_TOTAL*H + (size_t)(row0+yr)*H + yk
                              : nullptr;         // points at t=1
    const int yoff = yr*KPB + ((yk*2)^((yr&7)<<4));

    const int xr=tid/24, xk=tid-xr*24;           // IS_L0: 384 active threads
    const bool xact = IS_L0 && (tid < NB*24);
    const float* xbase = xact ? x + (size_t)(row0+xr)*(T_STEPS*24) + xk : nullptr;
    const int xoff = xr*KPB + ((xk*2)^((xr&7)<<4));

    // stage t=0 into buffer 0
    if constexpr (IS_L0){
        if (xact){
            float v=xbase[0];
            f16 vh=(f16)v, vl=(f16)(v-(float)vh);
            *(f16*)((char*)sh+xoff)=vh; *(f16*)((char*)sl+xoff)=vl;
        }
    } else {
        unsigned v=*(const unsigned*)(ys + (size_t)(row0+yr)*H + yk);
        *(unsigned*)((char*)sh+yoff)=v;
    }
    __syncthreads();

    const int aswz=(j15&7)<<4;
    const int abase=j15*KPB;
    // precomputed per-thread LDS offsets (constant across steps)
    int gw[4];                                   // gbuf write byte offsets (b64)
#pragma unroll
    for (int r=0;r<4;++r) gw[r]=(((4*g4+r)*GUP+u)*4+q0)*4;
    int grd[2], nho[2];
#pragma unroll
    for (int s2=0;s2<2;++s2){
        grd[s2]=((er0+s2)*GUP+eu)*16;            // gbuf read byte offset (b128)
        nho[s2]=(er0+s2)*KPB + (((F+eu)*2)^(((er0+s2)&7)<<4));
    }

#pragma unroll 1
    for (int t=0;t<T_STEPS;++t){
        const int cur=t&1, nxt=cur^1;
        const char* chb=(const char*)(sh+cur*BUF);
        const char* clb=HAS_LO ? (const char*)(sl+cur*BUF) : nullptr;
        char*       nhb=(char*)(sh+nxt*BUF);
        char*       nlb=HAS_LO ? (char*)(sl+nxt*BUF) : nullptr;

        // prefetch next input (incremental pointer); pin against sinking
        float xv=0.f; unsigned yv=0u;
        if (t+1<T_STEPS){
            if constexpr (IS_L0){ if (xact) xv = xbase[(size_t)(t+1)*24]; }
            else                { yv = *(const unsigned*)yld; yld += (size_t)B_TOTAL*H; }
        }
        __builtin_amdgcn_sched_barrier(0);

        // re-read h(t-1) dword from buf[cur] (drains at barrier1; stored after)
        unsigned hbits=0u;
        if (HAS_YSOUT && t>0) hbits = *(const unsigned*)(chb + ysrd_off);

        // ---- MFMA phase: 2 gates x parity-split chains ----
        f32x4 acc[2][2];
#pragma unroll
        for (int qq=0;qq<2;++qq){
            f32x4 a={bq[qq],bq[qq],bq[qq],bq[qq]}; acc[qq][0]=a;
            f32x4 z={0.f,0.f,0.f,0.f};              acc[qq][1]=z;
        }
#pragma unroll
        for (int s=0;s<KS;++s){
            int kb=((s*64+g4*16)^aswz);
            f16x8 ah=*(const f16x8*)(chb+abase+kb);
            if (s&1){
                acc[0][1]=__builtin_amdgcn_mfma_f32_16x16x32_f16(ah,Bf[0][s],acc[0][1],0,0,0);
                acc[1][1]=__builtin_amdgcn_mfma_f32_16x16x32_f16(ah,Bf[1][s],acc[1][1],0,0,0);
            } else {
                acc[0][0]=__builtin_amdgcn_mfma_f32_16x16x32_f16(ah,Bf[0][s],acc[0][0],0,0,0);
                acc[1][0]=__builtin_amdgcn_mfma_f32_16x16x32_f16(ah,Bf[1][s],acc[1][0],0,0,0);
            }
        }
        if constexpr (HAS_LO){
            int kb=((g4*16)^aswz);
            f16x8 al=*(const f16x8*)(clb+abase+kb);
            acc[0][1]=__builtin_amdgcn_mfma_f32_16x16x32_f16(al,Bf[0][0],acc[0][1],0,0,0);
            acc[1][1]=__builtin_amdgcn_mfma_f32_16x16x32_f16(al,Bf[1][0],acc[1][1],0,0,0);
        }
        // gates -> gbuf packed: one ds_write_b64 per row (both gates)
#pragma unroll
        for (int r=0;r<4;++r){
            f32x2 p={acc[0][0][r]+acc[0][1][r], acc[1][0][r]+acc[1][1][r]};
            *(f32x2*)((char*)gbuf + gw[r]) = p;
        }
        lds_barrier();   // gates + hbits drained

        // coalesced ys store of h(t-1): fire-and-forget dword
        if (HAS_YSOUT && t>0){ *ysst = hbits; ysst += ((size_t)B_TOTAL*H)/2; }

        // ---- elementwise: 2 cells, 1 ds_read_b128 each ----
#pragma unroll
        for (int s2=0;s2<2;++s2){
            f32x4 gv4 = *(const f32x4*)((const char*)gbuf + grd[s2]);
            float iv=sigf(gv4[0]), fv=sigf(gv4[1]);
            float gg=tanhf_(gv4[2]), ov=sigf(gv4[3]);
            float c=fv*c2[s2]+iv*gg;
            c2[s2]=c;
            float h=ov*tanhf_(c);
            *(f16*)(nhb + nho[s2]) = (f16)h;
            if constexpr (WRITE_HN){ if (t==T_STEPS-1) hn1g[(size_t)(row0+er0+s2)*H+eu]=h; }
            if constexpr (IS_LAST) { if (t==T_STEPS-1) hsum[(er0+s2)*96+eu]=h; }
        }
        // staged input -> buf[nxt]
        if (t+1<T_STEPS){
            if constexpr (IS_L0){
                if (xact){
                    f16 vh=(f16)xv, vl=(f16)(xv-(float)vh);
                    *(f16*)(nhb+xoff)=vh; *(f16*)(nlb+xoff)=vl;
                }
            } else {
                *(unsigned*)(nhb+yoff)=yv;
            }
        }
        lds_barrier();   // h + staged input visible for next step
    }
    // final ys store: h(T-1) sits in buf[T&1 == 0]
    if constexpr (HAS_YSOUT){
        unsigned hbits = *(const unsigned*)((const char*)sh + ysrd_off);
        asm volatile("s_waitcnt lgkmcnt(0)" ::: "memory");
        *ysst = hbits;
    }

    if constexpr (IS_LAST){
        // hsum = h3(T-1) + hn1 (global, from layer-1 kernel), then fused head
        {
            float2 v=*(const float2*)(hn1g + (size_t)row0*96 + tid*2);
            hsum[tid*2+0]+=v.x; hsum[tid*2+1]+=v.y;
        }
        __syncthreads();
        if (tid<256){
            int r=tid>>4, jj=tid&15;
            float a=fc1_b[jj];
            for (int uu=0;uu<96;++uu) a+=fc1_w[jj*96+uu]*fmaxf(hsum[r*96+uu],0.f);
            z1[r*16+jj]=fmaxf(a,0.f);
        }
        __syncthreads();
        if (tid<128){
            int r=tid>>3, jj=tid&7;
            float a=fc2_b[jj];
#pragma unroll
            for (int uu=0;uu<16;++uu) a+=fc2_w[jj*16+uu]*z1[r*16+uu];
            z2[r*8+jj]=fmaxf(a,0.f);
        }
        __syncthreads();
        if (tid<16){
            float a=fc3_b[0];
#pragma unroll
            for (int uu=0;uu<8;++uu) a+=fc3_w[uu]*z2[tid*8+uu];
            out[row0+tid]=a;
        }
    }
}

extern "C" void kernel_launch(void* const* d_in, const int* in_sizes, int n_in,
                              void* d_out, int out_size, void* d_ws, size_t ws_size,
                              hipStream_t stream) {
    const float* x         = (const float*)d_in[0];
    const float* W_ih0     = (const float*)d_in[1];
    const float* W_ih_rest = (const float*)d_in[2];
    const float* W_hh      = (const float*)d_in[3];
    const float* b_ih      = (const float*)d_in[4];
    const float* b_hh      = (const float*)d_in[5];
    const float* fc1_w     = (const float*)d_in[6];
    const float* fc1_b     = (const float*)d_in[7];
    const float* fc2_w     = (const float*)d_in[8];
    const float* fc2_b     = (const float*)d_in[9];
    const float* fc3_w     = (const float*)d_in[10];
    const float* fc3_b     = (const float*)d_in[11];
    float* out = (float*)d_out;

    const size_t YS = (size_t)T_STEPS * B_TOTAL * H * sizeof(f16);   // ~100.7 MB
    const size_t HN = (size_t)B_TOTAL * H * sizeof(float);           // ~1.6 MB
    if (ws_size < YS + HN) {
        hipMemsetAsync(d_out, 0, (size_t)out_size * sizeof(float), stream);
        return;
    }
    f16*   ys   = (f16*)d_ws;
    float* hn1g = (float*)((char*)d_ws + YS);

    const int GH = 384 * 96;

    // layer 0: x -> ys
    lstm_seq<24, true,  true,  false, false><<<NBLK, NTH, 0, stream>>>(
        x, ys, W_ih0, W_hh, b_ih, b_hh, hn1g,
        fc1_w, fc1_b, fc2_w, fc2_b, fc3_w, fc3_b, out);
    // layer 1: ys -> ys (in-place), hn1 -> global
    lstm_seq<96, false, true,  true,  false><<<NBLK, NTH, 0, stream>>>(
        nullptr, ys, W_ih_rest,        W_hh + 1*GH, b_ih + 1*384, b_hh + 1*384, hn1g,
        fc1_w, fc1_b, fc2_w, fc2_b, fc3_w, fc3_b, out);
    // layer 2: ys -> ys
    lstm_seq<96, false, true,  false, false><<<NBLK, NTH, 0, stream>>>(
        nullptr, ys, W_ih_rest + 1*GH, W_hh + 2*GH, b_ih + 2*384, b_hh + 2*384, hn1g,
        fc1_w, fc1_b, fc2_w, fc2_b, fc3_w, fc3_b, out);
    // layer 3: ys -> (head fused) -> out
    lstm_seq<96, false, false, false, true ><<<NBLK, NTH, 0, stream>>>(
        nullptr, ys, W_ih_rest + 2*GH, W_hh + 3*GH, b_ih + 3*384, b_hh + 3*384, hn1g,
        fc1_w, fc1_b, fc2_w, fc2_b, fc3_w, fc3_b, out);
}

// Round 16
// 858.842 us; speedup vs baseline: 1.0047x; 1.0047x over previous
//
#include <hip/hip_runtime.h>
#include <math.h>

typedef _Float16 f16;
typedef _Float16 f16x8 __attribute__((ext_vector_type(8)));
typedef float f32x4 __attribute__((ext_vector_type(4)));
typedef float f32x2 __attribute__((ext_vector_type(2)));

#define B_TOTAL 4096
#define T_STEPS 128
#define H 96
#define NB 16               // batch rows per block (one 16-row MFMA m-tile)
#define NTH 768             // 12 waves = 3 waves/SIMD
#define NBLK (B_TOTAL/NB)   // 256 blocks = 1 per CU
#define GUP 97              // gbuf unit stride in cells (pad -> <=2-way conflicts)

__device__ __forceinline__ float sigf(float v){ return 1.f/(1.f+__expf(-v)); }
__device__ __forceinline__ float tanhf_(float v){ float e=__expf(2.f*v); return 1.f-2.f/(e+1.f); }

// LDS-only barrier: no vmcnt(0) drain; orders LDS traffic only (R13-proven).
__device__ __forceinline__ void lds_barrier(){
    __builtin_amdgcn_sched_barrier(0);
    asm volatile("s_waitcnt lgkmcnt(0)" ::: "memory");
    __builtin_amdgcn_s_barrier();
    __builtin_amdgcn_sched_barrier(0);
}

// One LSTM layer per kernel, sequential over T. R15 structure + R16 change:
// 2-DEEP ys prefetch. The ys[t+1] global load was issued and consumed within
// one step -> its ~1000cy far-L2/L3 latency stalled the end-of-step barrier
// every step (evidence: L0 kernel without the load runs 0.75us/step vs 2.0).
// Now: yvA holds ys[t+1] (loaded during step t-1), step t issues ys[t+2]->yvB,
// writes yvA to LDS, swaps. The load gets a full step (~4800cy) of slack.
template<int F, bool IS_L0, bool HAS_YSOUT, bool WRITE_HN, bool IS_LAST>
__global__ __launch_bounds__(NTH, 1)
void lstm_seq(const float* __restrict__ x,     // IS_L0 input
              f16* __restrict__ ys,            // relay [T][B][H] f16 (in/out)
              const float* __restrict__ Wi, const float* __restrict__ Wh,
              const float* __restrict__ bi, const float* __restrict__ bh,
              float* __restrict__ hn1g,        // WRITE_HN: store; IS_LAST: load
              const float* __restrict__ fc1_w, const float* __restrict__ fc1_b,
              const float* __restrict__ fc2_w, const float* __restrict__ fc2_b,
              const float* __restrict__ fc3_w, const float* __restrict__ fc3_b,
              float* __restrict__ out)
{
    constexpr int  KS   = (F + H + 31)/32;   // 4 (F=24) or 6 (F=96)
    constexpr int  KP   = KS*32;
    constexpr int  KPB  = KP*2;              // bytes per act row
    constexpr bool HAS_LO = IS_L0;           // lo plane only for x (slice 0)
    constexpr int  BUF  = 16*KP;             // halves per buffer

    __shared__ f16 sh[2*BUF];                    // hi act plane, double-buffered
    __shared__ f16 sl[HAS_LO ? 2*BUF : 64];      // lo plane (L0 only)
    __shared__ float gbuf[16*GUP*4];             // [row][unit(pad)][gate] f32
    __shared__ float hsum[IS_LAST ? 16*96 : 16];
    __shared__ float z1[IS_LAST ? 16*16 : 16];
    __shared__ float z2[IS_LAST ? 16*8  : 16];

    const int tid=threadIdx.x, lane=tid&63, w=tid>>6;   // w: 0..11
    const int j15=lane&15, g4=lane>>4;
    const int g  = w>>1;                     // unit group 0..5
    const int q0 = (w&1)*2;                  // gates q0, q0+1
    const int u  = 16*g + j15;               // unit 0..95 (MFMA role)
    const int row0=blockIdx.x*NB;

    // elementwise role: 2 cells per thread
    const int eu  = tid>>3;                  // unit 0..95
    const int er0 = (tid&7)*2;               // rows er0, er0+1

    // ys store/re-read role: row sr, unit pair su (coalesced dword)
    const int sr = tid/48, su = (tid - sr*48)*2;
    const int ysrd_off = sr*KPB + (((F+su)*2) ^ ((sr&7)<<4));   // byte off in buf

    for (int i=tid;i<2*BUF;i+=NTH) sh[i]=(f16)0.f;
    if constexpr (HAS_LO)
        for (int i=tid;i<2*BUF;i+=NTH) sl[i]=(f16)0.f;

    // weight B-frags: lane holds W[j=96*(q0+qq)+u][k=32s+8*g4+e]
    f16x8 Bf[2][KS];
#pragma unroll
    for (int qq=0;qq<2;++qq){
        const int j=96*(q0+qq)+u;
#pragma unroll
        for (int s=0;s<KS;++s){
            f16x8 f;
#pragma unroll
            for (int e=0;e<8;++e){
                int k=32*s+8*g4+e;
                float v=0.f;
                if (k<F)        v=Wi[(size_t)j*F+k];
                else if (k-F<H) v=Wh[(size_t)j*H+(k-F)];
                f[e]=(f16)v;
            }
            Bf[qq][s]=f;
        }
    }
    float bq[2];
#pragma unroll
    for (int qq=0;qq<2;++qq) bq[qq]=bi[96*(q0+qq)+u]+bh[96*(q0+qq)+u];

    float c2[2]={0.f,0.f};

    // incremental global pointers
    unsigned* ysst = nullptr;                // store target (starts at t=0 slot)
    if constexpr (HAS_YSOUT)
        ysst = (unsigned*)(ys + (size_t)(row0+sr)*H + su);

    const int yi=tid*2, yr=yi/H, yk=yi-yr*H;     // prefetch role: 1 dword each
    const f16* yld = (!IS_L0) ? ys + (size_t)B_TOTAL*H + (size_t)(row0+yr)*H + yk
                              : nullptr;         // points at t=1
    const int yoff = yr*KPB + ((yk*2)^((yr&7)<<4));

    const int xr=tid/24, xk=tid-xr*24;           // IS_L0: 384 active threads
    const bool xact = IS_L0 && (tid < NB*24);
    const float* xbase = xact ? x + (size_t)(row0+xr)*(T_STEPS*24) + xk : nullptr;
    const int xoff = xr*KPB + ((xk*2)^((xr&7)<<4));

    // stage t=0 into buffer 0
    if constexpr (IS_L0){
        if (xact){
            float v=xbase[0];
            f16 vh=(f16)v, vl=(f16)(v-(float)vh);
            *(f16*)((char*)sh+xoff)=vh; *(f16*)((char*)sl+xoff)=vl;
        }
    } else {
        unsigned v=*(const unsigned*)(ys + (size_t)(row0+yr)*H + yk);
        *(unsigned*)((char*)sh+yoff)=v;
    }
    __syncthreads();

    // prologue of the 2-deep prefetch: yvA <- ys[1]
    unsigned yvA=0u;
    if constexpr (!IS_L0){
        yvA = *(const unsigned*)yld;
        yld += (size_t)B_TOTAL*H;            // now points at t=2
    }

    const int aswz=(j15&7)<<4;
    const int abase=j15*KPB;
    // precomputed per-thread LDS offsets (constant across steps)
    int gw[4];                                   // gbuf write byte offsets (b64)
#pragma unroll
    for (int r=0;r<4;++r) gw[r]=(((4*g4+r)*GUP+u)*4+q0)*4;
    int grd[2], nho[2];
#pragma unroll
    for (int s2=0;s2<2;++s2){
        grd[s2]=((er0+s2)*GUP+eu)*16;            // gbuf read byte offset (b128)
        nho[s2]=(er0+s2)*KPB + (((F+eu)*2)^(((er0+s2)&7)<<4));
    }

#pragma unroll 1
    for (int t=0;t<T_STEPS;++t){
        const int cur=t&1, nxt=cur^1;
        const char* chb=(const char*)(sh+cur*BUF);
        const char* clb=HAS_LO ? (const char*)(sl+cur*BUF) : nullptr;
        char*       nhb=(char*)(sh+nxt*BUF);
        char*       nlb=HAS_LO ? (char*)(sl+nxt*BUF) : nullptr;

        // issue prefetch for t+2 (lands during this AND next step)
        float xv=0.f; unsigned yvB=0u;
        if constexpr (IS_L0){
            if (xact && t+1<T_STEPS) xv = xbase[(size_t)(t+1)*24];
        } else {
            if (t+2<T_STEPS){ yvB = *(const unsigned*)yld; yld += (size_t)B_TOTAL*H; }
        }
        __builtin_amdgcn_sched_barrier(0);

        // re-read h(t-1) dword from buf[cur] (drains at barrier1; stored after)
        unsigned hbits=0u;
        if (HAS_YSOUT && t>0) hbits = *(const unsigned*)(chb + ysrd_off);

        // ---- MFMA phase: 2 gates x parity-split chains ----
        f32x4 acc[2][2];
#pragma unroll
        for (int qq=0;qq<2;++qq){
            f32x4 a={bq[qq],bq[qq],bq[qq],bq[qq]}; acc[qq][0]=a;
            f32x4 z={0.f,0.f,0.f,0.f};              acc[qq][1]=z;
        }
#pragma unroll
        for (int s=0;s<KS;++s){
            int kb=((s*64+g4*16)^aswz);
            f16x8 ah=*(const f16x8*)(chb+abase+kb);
            if (s&1){
                acc[0][1]=__builtin_amdgcn_mfma_f32_16x16x32_f16(ah,Bf[0][s],acc[0][1],0,0,0);
                acc[1][1]=__builtin_amdgcn_mfma_f32_16x16x32_f16(ah,Bf[1][s],acc[1][1],0,0,0);
            } else {
                acc[0][0]=__builtin_amdgcn_mfma_f32_16x16x32_f16(ah,Bf[0][s],acc[0][0],0,0,0);
                acc[1][0]=__builtin_amdgcn_mfma_f32_16x16x32_f16(ah,Bf[1][s],acc[1][0],0,0,0);
            }
        }
        if constexpr (HAS_LO){
            int kb=((g4*16)^aswz);
            f16x8 al=*(const f16x8*)(clb+abase+kb);
            acc[0][1]=__builtin_amdgcn_mfma_f32_16x16x32_f16(al,Bf[0][0],acc[0][1],0,0,0);
            acc[1][1]=__builtin_amdgcn_mfma_f32_16x16x32_f16(al,Bf[1][0],acc[1][1],0,0,0);
        }
        // gates -> gbuf packed: one ds_write_b64 per row (both gates)
#pragma unroll
        for (int r=0;r<4;++r){
            f32x2 p={acc[0][0][r]+acc[0][1][r], acc[1][0][r]+acc[1][1][r]};
            *(f32x2*)((char*)gbuf + gw[r]) = p;
        }
        lds_barrier();   // gates + hbits drained

        // coalesced ys store of h(t-1): fire-and-forget dword
        if (HAS_YSOUT && t>0){ *ysst = hbits; ysst += ((size_t)B_TOTAL*H)/2; }

        // ---- elementwise: 2 cells, 1 ds_read_b128 each ----
#pragma unroll
        for (int s2=0;s2<2;++s2){
            f32x4 gv4 = *(const f32x4*)((const char*)gbuf + grd[s2]);
            float iv=sigf(gv4[0]), fv=sigf(gv4[1]);
            float gg=tanhf_(gv4[2]), ov=sigf(gv4[3]);
            float c=fv*c2[s2]+iv*gg;
            c2[s2]=c;
            float h=ov*tanhf_(c);
            *(f16*)(nhb + nho[s2]) = (f16)h;
            if constexpr (WRITE_HN){ if (t==T_STEPS-1) hn1g[(size_t)(row0+er0+s2)*H+eu]=h; }
            if constexpr (IS_LAST) { if (t==T_STEPS-1) hsum[(er0+s2)*96+eu]=h; }
        }
        // staged input -> buf[nxt]: write yvA (= ys[t+1], loaded a step ago)
        if (t+1<T_STEPS){
            if constexpr (IS_L0){
                if (xact){
                    f16 vh=(f16)xv, vl=(f16)(xv-(float)vh);
                    *(f16*)(nhb+xoff)=vh; *(f16*)(nlb+xoff)=vl;
                }
            } else {
                *(unsigned*)(nhb+yoff)=yvA;
            }
        }
        lds_barrier();   // h + staged input visible for next step
        yvA = yvB;       // rotate the 2-deep pipeline (scalar, stays in VGPR)
    }
    // final ys store: h(T-1) sits in buf[T&1 == 0]
    if constexpr (HAS_YSOUT){
        unsigned hbits = *(const unsigned*)((const char*)sh + ysrd_off);
        asm volatile("s_waitcnt lgkmcnt(0)" ::: "memory");
        *ysst = hbits;
    }

    if constexpr (IS_LAST){
        // hsum = h3(T-1) + hn1 (global, from layer-1 kernel), then fused head
        {
            float2 v=*(const float2*)(hn1g + (size_t)row0*96 + tid*2);
            hsum[tid*2+0]+=v.x; hsum[tid*2+1]+=v.y;
        }
        __syncthreads();
        if (tid<256){
            int r=tid>>4, jj=tid&15;
            float a=fc1_b[jj];
            for (int uu=0;uu<96;++uu) a+=fc1_w[jj*96+uu]*fmaxf(hsum[r*96+uu],0.f);
            z1[r*16+jj]=fmaxf(a,0.f);
        }
        __syncthreads();
        if (tid<128){
            int r=tid>>3, jj=tid&7;
            float a=fc2_b[jj];
#pragma unroll
            for (int uu=0;uu<16;++uu) a+=fc2_w[jj*16+uu]*z1[r*16+uu];
            z2[r*8+jj]=fmaxf(a,0.f);
        }
        __syncthreads();
        if (tid<16){
            float a=fc3_b[0];
#pragma unroll
            for (int uu=0;uu<8;++uu) a+=fc3_w[uu]*z2[tid*8+uu];
            out[row0+tid]=a;
        }
    }
}

extern "C" void kernel_launch(void* const* d_in, const int* in_sizes, int n_in,
                              void* d_out, int out_size, void* d_ws, size_t ws_size,
                              hipStream_t stream) {
    const float* x         = (const float*)d_in[0];
    const float* W_ih0     = (const float*)d_in[1];
    const float* W_ih_rest = (const float*)d_in[2];
    const float* W_hh      = (const float*)d_in[3];
    const float* b_ih      = (const float*)d_in[4];
    const float* b_hh      = (const float*)d_in[5];
    const float* fc1_w     = (const float*)d_in[6];
    const float* fc1_b     = (const float*)d_in[7];
    const float* fc2_w     = (const float*)d_in[8];
    const float* fc2_b     = (const float*)d_in[9];
    const float* fc3_w     = (const float*)d_in[10];
    const float* fc3_b     = (const float*)d_in[11];
    float* out = (float*)d_out;

    const size_t YS = (size_t)T_STEPS * B_TOTAL * H * sizeof(f16);   // ~100.7 MB
    const size_t HN = (size_t)B_TOTAL * H * sizeof(float);           // ~1.6 MB
    if (ws_size < YS + HN) {
        hipMemsetAsync(d_out, 0, (size_t)out_size * sizeof(float), stream);
        return;
    }
    f16*   ys   = (f16*)d_ws;
    float* hn1g = (float*)((char*)d_ws + YS);

    const int GH = 384 * 96;

    // layer 0: x -> ys
    lstm_seq<24, true,  true,  false, false><<<NBLK, NTH, 0, stream>>>(
        x, ys, W_ih0, W_hh, b_ih, b_hh, hn1g,
        fc1_w, fc1_b, fc2_w, fc2_b, fc3_w, fc3_b, out);
    // layer 1: ys -> ys (in-place), hn1 -> global
    lstm_seq<96, false, true,  true,  false><<<NBLK, NTH, 0, stream>>>(
        nullptr, ys, W_ih_rest,        W_hh + 1*GH, b_ih + 1*384, b_hh + 1*384, hn1g,
        fc1_w, fc1_b, fc2_w, fc2_b, fc3_w, fc3_b, out);
    // layer 2: ys -> ys
    lstm_seq<96, false, true,  false, false><<<NBLK, NTH, 0, stream>>>(
        nullptr, ys, W_ih_rest + 1*GH, W_hh + 2*GH, b_ih + 2*384, b_hh + 2*384, hn1g,
        fc1_w, fc1_b, fc2_w, fc2_b, fc3_w, fc3_b, out);
    // layer 3: ys -> (head fused) -> out
    lstm_seq<96, false, false, false, true ><<<NBLK, NTH, 0, stream>>>(
        nullptr, ys, W_ih_rest + 2*GH, W_hh + 3*GH, b_ih + 3*384, b_hh + 3*384, hn1g,
        fc1_w, fc1_b, fc2_w, fc2_b, fc3_w, fc3_b, out);
}

// Round 17
// 853.601 us; speedup vs baseline: 1.0108x; 1.0061x over previous
//
#include <hip/hip_runtime.h>
#include <math.h>

typedef _Float16 f16;
typedef _Float16 f16x8 __attribute__((ext_vector_type(8)));
typedef float f32x4 __attribute__((ext_vector_type(4)));
typedef float f32x2 __attribute__((ext_vector_type(2)));

#define B_TOTAL 4096
#define T_STEPS 128
#define H 96
#define NB 16               // batch rows per block
#define NTH 768             // 12 waves = 3 waves/SIMD
#define NBLK (B_TOTAL/NB)   // 256 blocks = 1 per CU
#define GUP 97              // gbuf unit stride (pad -> <=2-way conflicts)
#define ST_T (NB*H)         // f16 per strip timestep slot = 1536

__device__ __forceinline__ float sigf(float v){ return 1.f/(1.f+__expf(-v)); }
__device__ __forceinline__ float tanhf_(float v){ float e=__expf(2.f*v); return 1.f-2.f/(e+1.f); }

// LDS-only barrier: no vmcnt(0) drain (R13-proven safe here).
__device__ __forceinline__ void lds_barrier(){
    __builtin_amdgcn_sched_barrier(0);
    asm volatile("s_waitcnt lgkmcnt(0)" ::: "memory");
    __builtin_amdgcn_s_barrier();
    __builtin_amdgcn_sched_barrier(0);
}

// One LSTM layer over all T for this block's 16 rows. R16 inner loop verbatim;
// ys is now a BLOCK-PRIVATE strip [T][16][96] f16 (all role pointers = +tid).
// WRITE_HSUM: layer1 writes h(T-1) to hsum LDS; ADD_HSUM: layer3 adds.
template<int F, bool IS_L0, bool HAS_YSOUT, bool WRITE_HSUM, bool ADD_HSUM>
__device__ __forceinline__ void layer_run(
    const float* __restrict__ x32, f16* __restrict__ strip,
    const float* __restrict__ Wi, const float* __restrict__ Wh,
    const float* __restrict__ bi, const float* __restrict__ bh,
    f16* sh, f16* sl, float* gbuf, float* hsum, int row0)
{
    constexpr int  KS   = (F + H + 31)/32;   // 4 (F=24) or 6 (F=96)
    constexpr int  KP   = KS*32;
    constexpr int  KPB  = KP*2;
    constexpr bool HAS_LO = IS_L0;
    constexpr int  BUF  = 16*KP;

    const int tid=threadIdx.x, lane=tid&63, w=tid>>6;
    const int j15=lane&15, g4=lane>>4;
    const int g=w>>1, q0=(w&1)*2;
    const int u=16*g+j15;
    const int eu=tid>>3, er0=(tid&7)*2;
    const int sr=tid/48, su=(tid-sr*48)*2;
    const int ysrd_off = sr*KPB + (((F+su)*2) ^ ((sr&7)<<4));

    for (int i=tid;i<2*BUF;i+=NTH) sh[i]=(f16)0.f;
    if constexpr (HAS_LO)
        for (int i=tid;i<2*BUF;i+=NTH) sl[i]=(f16)0.f;

    // weight B-frags: lane holds W[j=96*(q0+qq)+u][k=32s+8*g4+e]
    f16x8 Bf[2][KS];
#pragma unroll
    for (int qq=0;qq<2;++qq){
        const int j=96*(q0+qq)+u;
#pragma unroll
        for (int s=0;s<KS;++s){
            f16x8 f;
#pragma unroll
            for (int e=0;e<8;++e){
                int k=32*s+8*g4+e;
                float v=0.f;
                if (k<F)        v=Wi[(size_t)j*F+k];
                else if (k-F<H) v=Wh[(size_t)j*H+(k-F)];
                f[e]=(f16)v;
            }
            Bf[qq][s]=f;
        }
    }
    float bq[2];
#pragma unroll
    for (int qq=0;qq<2;++qq) bq[qq]=bi[96*(q0+qq)+u]+bh[96*(q0+qq)+u];

    float c2[2]={0.f,0.f};

    // strip role pointers — all collapse to +tid on the block-private strip
    unsigned*       ysst = (unsigned*)strip + tid;           // store slot t=0
    const unsigned* yld  = (const unsigned*)strip + (ST_T/2) + tid;  // load t=1
    const int yr=(tid*2)/H, yk=(tid*2)-yr*H;
    const int yoff = yr*KPB + ((yk*2)^((yr&7)<<4));

    const int xr=tid/24, xk=tid-xr*24;
    const bool xact = IS_L0 && (tid < NB*24);
    const float* xbase = xact ? x32 + (size_t)(row0+xr)*(T_STEPS*24) + xk : nullptr;
    const int xoff = xr*KPB + ((xk*2)^((xr&7)<<4));

    // stage t=0 into buffer 0
    if constexpr (IS_L0){
        if (xact){
            float v=xbase[0];
            f16 vh=(f16)v, vl=(f16)(v-(float)vh);
            *(f16*)((char*)sh+xoff)=vh; *(f16*)((char*)sl+xoff)=vl;
        }
    } else {
        unsigned v = *((const unsigned*)strip + tid);
        *(unsigned*)((char*)sh+yoff)=v;
    }
    __syncthreads();

    // 2-deep prefetch prologue: yvA <- strip[1]
    unsigned yvA=0u;
    if constexpr (!IS_L0){ yvA = *yld; yld += ST_T/2; }

    const int aswz=(j15&7)<<4;
    const int abase=j15*KPB;
    int gw[4];
#pragma unroll
    for (int r=0;r<4;++r) gw[r]=(((4*g4+r)*GUP+u)*4+q0)*4;
    int grd[2], nho[2];
#pragma unroll
    for (int s2=0;s2<2;++s2){
        grd[s2]=((er0+s2)*GUP+eu)*16;
        nho[s2]=(er0+s2)*KPB + (((F+eu)*2)^(((er0+s2)&7)<<4));
    }

#pragma unroll 1
    for (int t=0;t<T_STEPS;++t){
        const int cur=t&1, nxt=cur^1;
        const char* chb=(const char*)(sh+cur*BUF);
        const char* clb=HAS_LO ? (const char*)(sl+cur*BUF) : nullptr;
        char*       nhb=(char*)(sh+nxt*BUF);
        char*       nlb=HAS_LO ? (char*)(sl+nxt*BUF) : nullptr;

        float xv=0.f; unsigned yvB=0u;
        if constexpr (IS_L0){
            if (xact && t+1<T_STEPS) xv = xbase[(size_t)(t+1)*24];
        } else {
            if (t+2<T_STEPS){ yvB = *yld; yld += ST_T/2; }
        }
        __builtin_amdgcn_sched_barrier(0);

        unsigned hbits=0u;
        if (HAS_YSOUT && t>0) hbits = *(const unsigned*)(chb + ysrd_off);

        // ---- MFMA phase: 2 gates x parity-split chains ----
        f32x4 acc[2][2];
#pragma unroll
        for (int qq=0;qq<2;++qq){
            f32x4 a={bq[qq],bq[qq],bq[qq],bq[qq]}; acc[qq][0]=a;
            f32x4 z={0.f,0.f,0.f,0.f};              acc[qq][1]=z;
        }
#pragma unroll
        for (int s=0;s<KS;++s){
            int kb=((s*64+g4*16)^aswz);
            f16x8 ah=*(const f16x8*)(chb+abase+kb);
            if (s&1){
                acc[0][1]=__builtin_amdgcn_mfma_f32_16x16x32_f16(ah,Bf[0][s],acc[0][1],0,0,0);
                acc[1][1]=__builtin_amdgcn_mfma_f32_16x16x32_f16(ah,Bf[1][s],acc[1][1],0,0,0);
            } else {
                acc[0][0]=__builtin_amdgcn_mfma_f32_16x16x32_f16(ah,Bf[0][s],acc[0][0],0,0,0);
                acc[1][0]=__builtin_amdgcn_mfma_f32_16x16x32_f16(ah,Bf[1][s],acc[1][0],0,0,0);
            }
        }
        if constexpr (HAS_LO){
            int kb=((g4*16)^aswz);
            f16x8 al=*(const f16x8*)(clb+abase+kb);
            acc[0][1]=__builtin_amdgcn_mfma_f32_16x16x32_f16(al,Bf[0][0],acc[0][1],0,0,0);
            acc[1][1]=__builtin_amdgcn_mfma_f32_16x16x32_f16(al,Bf[1][0],acc[1][1],0,0,0);
        }
#pragma unroll
        for (int r=0;r<4;++r){
            f32x2 p={acc[0][0][r]+acc[0][1][r], acc[1][0][r]+acc[1][1][r]};
            *(f32x2*)((char*)gbuf + gw[r]) = p;
        }
        lds_barrier();

        if (HAS_YSOUT && t>0){ *ysst = hbits; ysst += ST_T/2; }

        // ---- elementwise: 2 cells, 1 ds_read_b128 each ----
#pragma unroll
        for (int s2=0;s2<2;++s2){
            f32x4 gv4 = *(const f32x4*)((const char*)gbuf + grd[s2]);
            float iv=sigf(gv4[0]), fv=sigf(gv4[1]);
            float gg=tanhf_(gv4[2]), ov=sigf(gv4[3]);
            float c=fv*c2[s2]+iv*gg;
            c2[s2]=c;
            float h=ov*tanhf_(c);
            *(f16*)(nhb + nho[s2]) = (f16)h;
            if constexpr (WRITE_HSUM){ if (t==T_STEPS-1) hsum[(er0+s2)*96+eu]=h; }
            if constexpr (ADD_HSUM)  { if (t==T_STEPS-1) hsum[(er0+s2)*96+eu]+=h; }
        }
        if (t+1<T_STEPS){
            if constexpr (IS_L0){
                if (xact){
                    f16 vh=(f16)xv, vl=(f16)(xv-(float)vh);
                    *(f16*)(nhb+xoff)=vh; *(f16*)(nlb+xoff)=vl;
                }
            } else {
                *(unsigned*)(nhb+yoff)=yvA;
            }
        }
        lds_barrier();
        yvA = yvB;
    }
    // final strip store: h(T-1) sits in buf[0] (T even)
    if constexpr (HAS_YSOUT){
        unsigned hbits = *(const unsigned*)((const char*)sh + ysrd_off);
        asm volatile("s_waitcnt lgkmcnt(0)" ::: "memory");
        *ysst = hbits;
    }
}

__global__ __launch_bounds__(NTH, 1)
void lstm_all(const float* __restrict__ x,
              const float* __restrict__ W_ih0,
              const float* __restrict__ W_ih_rest,
              const float* __restrict__ W_hh,
              const float* __restrict__ b_ih,
              const float* __restrict__ b_hh,
              const float* __restrict__ fc1_w, const float* __restrict__ fc1_b,
              const float* __restrict__ fc2_w, const float* __restrict__ fc2_b,
              const float* __restrict__ fc3_w, const float* __restrict__ fc3_b,
              f16* __restrict__ ws_strip, float* __restrict__ out)
{
    __shared__ f16 sh[2*16*192];           // act hi (max KP=192), double-buffered
    __shared__ f16 sl[2*16*128];           // act lo (L0 only, KP=128)
    __shared__ float gbuf[16*GUP*4];
    __shared__ float hsum[16*96];
    __shared__ float z1[16*16];
    __shared__ float z2[16*8];

    const int tid=threadIdx.x;
    const int b=blockIdx.x, row0=b*NB;
    f16* strip = ws_strip + (size_t)b*T_STEPS*ST_T;
    const int GH = 384*96;

    layer_run<24, true,  true,  false, false>(x, strip, W_ih0,             W_hh,        b_ih,          b_hh,          sh,sl,gbuf,hsum,row0);
    __syncthreads();
    layer_run<96, false, true,  true,  false>(nullptr, strip, W_ih_rest,        W_hh+1*GH, b_ih+1*384, b_hh+1*384, sh,sl,gbuf,hsum,row0);
    __syncthreads();
    layer_run<96, false, true,  false, false>(nullptr, strip, W_ih_rest+1*GH, W_hh+2*GH, b_ih+2*384, b_hh+2*384, sh,sl,gbuf,hsum,row0);
    __syncthreads();
    layer_run<96, false, false, false, true >(nullptr, strip, W_ih_rest+2*GH, W_hh+3*GH, b_ih+3*384, b_hh+3*384, sh,sl,gbuf,hsum,row0);
    __syncthreads();

    // ---- fused head: relu(hsum) -> fc1 -> relu -> fc2 -> relu -> fc3 ----
    if (tid<256){
        int r=tid>>4, jj=tid&15;
        float a=fc1_b[jj];
        for (int uu=0;uu<96;++uu) a+=fc1_w[jj*96+uu]*fmaxf(hsum[r*96+uu],0.f);
        z1[r*16+jj]=fmaxf(a,0.f);
    }
    __syncthreads();
    if (tid<128){
        int r=tid>>3, jj=tid&7;
        float a=fc2_b[jj];
#pragma unroll
        for (int uu=0;uu<16;++uu) a+=fc2_w[jj*16+uu]*z1[r*16+uu];
        z2[r*8+jj]=fmaxf(a,0.f);
    }
    __syncthreads();
    if (tid<16){
        float a=fc3_b[0];
#pragma unroll
        for (int uu=0;uu<8;++uu) a+=fc3_w[uu]*z2[tid*8+uu];
        out[row0+tid]=a;
    }
}

extern "C" void kernel_launch(void* const* d_in, const int* in_sizes, int n_in,
                              void* d_out, int out_size, void* d_ws, size_t ws_size,
                              hipStream_t stream) {
    const float* x         = (const float*)d_in[0];
    const float* W_ih0     = (const float*)d_in[1];
    const float* W_ih_rest = (const float*)d_in[2];
    const float* W_hh      = (const float*)d_in[3];
    const float* b_ih      = (const float*)d_in[4];
    const float* b_hh      = (const float*)d_in[5];
    const float* fc1_w     = (const float*)d_in[6];
    const float* fc1_b     = (const float*)d_in[7];
    const float* fc2_w     = (const float*)d_in[8];
    const float* fc2_b     = (const float*)d_in[9];
    const float* fc3_w     = (const float*)d_in[10];
    const float* fc3_b     = (const float*)d_in[11];
    float* out = (float*)d_out;

    const size_t WS = (size_t)NBLK * T_STEPS * ST_T * sizeof(f16);  // ~100.7 MB
    if (ws_size < WS) {
        hipMemsetAsync(d_out, 0, (size_t)out_size * sizeof(float), stream);
        return;
    }

    lstm_all<<<dim3(NBLK), dim3(NTH), 0, stream>>>(
        x, W_ih0, W_ih_rest, W_hh, b_ih, b_hh,
        fc1_w, fc1_b, fc2_w, fc2_b, fc3_w, fc3_b,
        (f16*)d_ws, out);
}

// Round 18
// 612.743 us; speedup vs baseline: 1.4082x; 1.3931x over previous
//
#include <hip/hip_runtime.h>
#include <math.h>

typedef _Float16 f16;
typedef _Float16 f16x8 __attribute__((ext_vector_type(8)));
typedef float f32x4 __attribute__((ext_vector_type(4)));
typedef float f32x2 __attribute__((ext_vector_type(2)));

#define B_TOTAL 4096
#define T_STEPS 128
#define H 96
#define NB 16               // batch rows per block
#define NTH 768             // 12 waves = 3 waves/SIMD
#define NBLK (B_TOTAL/NB)   // 256 blocks = 1 per CU
#define GUP 97              // gbuf unit stride (pad -> <=2-way conflicts)
#define ST_T (NB*H)         // f16 per strip timestep slot = 1536

// R18: hardware-reciprocal nonlinearities. The old 1/x and 2/(x) forms were
// IEEE-division-expanded by hipcc (~8-10 VALU instr each, 5 divs/cell =
// ~90 hidden instr/thread/step). v_rcp_f32 is 1 instr, ~1ulp — absmax budget
// (6.1e-5 vs 2.89e-4 threshold) absorbs it.
__device__ __forceinline__ float sigf(float v){
    return __builtin_amdgcn_rcpf(1.f + __expf(-v));
}
__device__ __forceinline__ float tanhf_(float v){
    return 1.f - 2.f*__builtin_amdgcn_rcpf(__expf(2.f*v) + 1.f);
}

// LDS-only barrier: no vmcnt(0) drain (R13-proven safe here).
__device__ __forceinline__ void lds_barrier(){
    __builtin_amdgcn_sched_barrier(0);
    asm volatile("s_waitcnt lgkmcnt(0)" ::: "memory");
    __builtin_amdgcn_s_barrier();
    __builtin_amdgcn_sched_barrier(0);
}

// One LSTM layer over all T for this block's 16 rows (R17 structure).
template<int F, bool IS_L0, bool HAS_YSOUT, bool WRITE_HSUM, bool ADD_HSUM>
__device__ __forceinline__ void layer_run(
    const float* __restrict__ x32, f16* __restrict__ strip,
    const float* __restrict__ Wi, const float* __restrict__ Wh,
    const float* __restrict__ bi, const float* __restrict__ bh,
    f16* sh, f16* sl, float* gbuf, float* hsum, int row0)
{
    constexpr int  KS   = (F + H + 31)/32;   // 4 (F=24) or 6 (F=96)
    constexpr int  KP   = KS*32;
    constexpr int  KPB  = KP*2;
    constexpr bool HAS_LO = IS_L0;
    constexpr int  BUF  = 16*KP;

    const int tid=threadIdx.x, lane=tid&63, w=tid>>6;
    const int j15=lane&15, g4=lane>>4;
    const int g=w>>1, q0=(w&1)*2;
    const int u=16*g+j15;
    const int eu=tid>>3, er0=(tid&7)*2;
    const int sr=tid/48, su=(tid-sr*48)*2;
    const int ysrd_off = sr*KPB + (((F+su)*2) ^ ((sr&7)<<4));

    for (int i=tid;i<2*BUF;i+=NTH) sh[i]=(f16)0.f;
    if constexpr (HAS_LO)
        for (int i=tid;i<2*BUF;i+=NTH) sl[i]=(f16)0.f;

    // weight B-frags: lane holds W[j=96*(q0+qq)+u][k=32s+8*g4+e]
    f16x8 Bf[2][KS];
#pragma unroll
    for (int qq=0;qq<2;++qq){
        const int j=96*(q0+qq)+u;
#pragma unroll
        for (int s=0;s<KS;++s){
            f16x8 f;
#pragma unroll
            for (int e=0;e<8;++e){
                int k=32*s+8*g4+e;
                float v=0.f;
                if (k<F)        v=Wi[(size_t)j*F+k];
                else if (k-F<H) v=Wh[(size_t)j*H+(k-F)];
                f[e]=(f16)v;
            }
            Bf[qq][s]=f;
        }
    }
    float bq[2];
#pragma unroll
    for (int qq=0;qq<2;++qq) bq[qq]=bi[96*(q0+qq)+u]+bh[96*(q0+qq)+u];

    float c2[2]={0.f,0.f};

    // strip role pointers — all collapse to +tid on the block-private strip
    unsigned*       ysst = (unsigned*)strip + tid;           // store slot t=0
    const unsigned* yld  = (const unsigned*)strip + (ST_T/2) + tid;  // load t=1
    const int yr=(tid*2)/H, yk=(tid*2)-yr*H;
    const int yoff = yr*KPB + ((yk*2)^((yr&7)<<4));

    const int xr=tid/24, xk=tid-xr*24;
    const bool xact = IS_L0 && (tid < NB*24);
    const float* xbase = xact ? x32 + (size_t)(row0+xr)*(T_STEPS*24) + xk : nullptr;
    const int xoff = xr*KPB + ((xk*2)^((xr&7)<<4));

    // stage t=0 into buffer 0
    if constexpr (IS_L0){
        if (xact){
            float v=xbase[0];
            f16 vh=(f16)v, vl=(f16)(v-(float)vh);
            *(f16*)((char*)sh+xoff)=vh; *(f16*)((char*)sl+xoff)=vl;
        }
    } else {
        unsigned v = *((const unsigned*)strip + tid);
        *(unsigned*)((char*)sh+yoff)=v;
    }
    __syncthreads();

    // 2-deep prefetch prologue: yvA <- strip[1]
    unsigned yvA=0u;
    if constexpr (!IS_L0){ yvA = *yld; yld += ST_T/2; }

    const int aswz=(j15&7)<<4;
    const int abase=j15*KPB;
    int gw[4];
#pragma unroll
    for (int r=0;r<4;++r) gw[r]=(((4*g4+r)*GUP+u)*4+q0)*4;
    int grd[2], nho[2];
#pragma unroll
    for (int s2=0;s2<2;++s2){
        grd[s2]=((er0+s2)*GUP+eu)*16;
        nho[s2]=(er0+s2)*KPB + (((F+eu)*2)^(((er0+s2)&7)<<4));
    }

#pragma unroll 1
    for (int t=0;t<T_STEPS;++t){
        const int cur=t&1, nxt=cur^1;
        const char* chb=(const char*)(sh+cur*BUF);
        const char* clb=HAS_LO ? (const char*)(sl+cur*BUF) : nullptr;
        char*       nhb=(char*)(sh+nxt*BUF);
        char*       nlb=HAS_LO ? (char*)(sl+nxt*BUF) : nullptr;

        float xv=0.f; unsigned yvB=0u;
        if constexpr (IS_L0){
            if (xact && t+1<T_STEPS) xv = xbase[(size_t)(t+1)*24];
        } else {
            if (t+2<T_STEPS){ yvB = *yld; yld += ST_T/2; }
        }
        __builtin_amdgcn_sched_barrier(0);

        unsigned hbits=0u;
        if (HAS_YSOUT && t>0) hbits = *(const unsigned*)(chb + ysrd_off);

        // ---- MFMA phase: 2 gates x parity-split chains ----
        f32x4 acc[2][2];
#pragma unroll
        for (int qq=0;qq<2;++qq){
            f32x4 a={bq[qq],bq[qq],bq[qq],bq[qq]}; acc[qq][0]=a;
            f32x4 z={0.f,0.f,0.f,0.f};              acc[qq][1]=z;
        }
#pragma unroll
        for (int s=0;s<KS;++s){
            int kb=((s*64+g4*16)^aswz);
            f16x8 ah=*(const f16x8*)(chb+abase+kb);
            if (s&1){
                acc[0][1]=__builtin_amdgcn_mfma_f32_16x16x32_f16(ah,Bf[0][s],acc[0][1],0,0,0);
                acc[1][1]=__builtin_amdgcn_mfma_f32_16x16x32_f16(ah,Bf[1][s],acc[1][1],0,0,0);
            } else {
                acc[0][0]=__builtin_amdgcn_mfma_f32_16x16x32_f16(ah,Bf[0][s],acc[0][0],0,0,0);
                acc[1][0]=__builtin_amdgcn_mfma_f32_16x16x32_f16(ah,Bf[1][s],acc[1][0],0,0,0);
            }
        }
        if constexpr (HAS_LO){
            int kb=((g4*16)^aswz);
            f16x8 al=*(const f16x8*)(clb+abase+kb);
            acc[0][1]=__builtin_amdgcn_mfma_f32_16x16x32_f16(al,Bf[0][0],acc[0][1],0,0,0);
            acc[1][1]=__builtin_amdgcn_mfma_f32_16x16x32_f16(al,Bf[1][0],acc[1][1],0,0,0);
        }
#pragma unroll
        for (int r=0;r<4;++r){
            f32x2 p={acc[0][0][r]+acc[0][1][r], acc[1][0][r]+acc[1][1][r]};
            *(f32x2*)((char*)gbuf + gw[r]) = p;
        }
        lds_barrier();

        if (HAS_YSOUT && t>0){ *ysst = hbits; ysst += ST_T/2; }

        // ---- elementwise: 2 cells, 1 ds_read_b128 each ----
#pragma unroll
        for (int s2=0;s2<2;++s2){
            f32x4 gv4 = *(const f32x4*)((const char*)gbuf + grd[s2]);
            float iv=sigf(gv4[0]), fv=sigf(gv4[1]);
            float gg=tanhf_(gv4[2]), ov=sigf(gv4[3]);
            float c=fv*c2[s2]+iv*gg;
            c2[s2]=c;
            float h=ov*tanhf_(c);
            *(f16*)(nhb + nho[s2]) = (f16)h;
            if constexpr (WRITE_HSUM){ if (t==T_STEPS-1) hsum[(er0+s2)*96+eu]=h; }
            if constexpr (ADD_HSUM)  { if (t==T_STEPS-1) hsum[(er0+s2)*96+eu]+=h; }
        }
        if (t+1<T_STEPS){
            if constexpr (IS_L0){
                if (xact){
                    f16 vh=(f16)xv, vl=(f16)(xv-(float)vh);
                    *(f16*)(nhb+xoff)=vh; *(f16*)(nlb+xoff)=vl;
                }
            } else {
                *(unsigned*)(nhb+yoff)=yvA;
            }
        }
        lds_barrier();
        yvA = yvB;
    }
    // final strip store: h(T-1) sits in buf[0] (T even)
    if constexpr (HAS_YSOUT){
        unsigned hbits = *(const unsigned*)((const char*)sh + ysrd_off);
        asm volatile("s_waitcnt lgkmcnt(0)" ::: "memory");
        *ysst = hbits;
    }
}

__global__ __launch_bounds__(NTH, 1)
void lstm_all(const float* __restrict__ x,
              const float* __restrict__ W_ih0,
              const float* __restrict__ W_ih_rest,
              const float* __restrict__ W_hh,
              const float* __restrict__ b_ih,
              const float* __restrict__ b_hh,
              const float* __restrict__ fc1_w, const float* __restrict__ fc1_b,
              const float* __restrict__ fc2_w, const float* __restrict__ fc2_b,
              const float* __restrict__ fc3_w, const float* __restrict__ fc3_b,
              f16* __restrict__ ws_strip, float* __restrict__ out)
{
    __shared__ f16 sh[2*16*192];           // act hi (max KP=192), double-buffered
    __shared__ f16 sl[2*16*128];           // act lo (L0 only, KP=128)
    __shared__ float gbuf[16*GUP*4];
    __shared__ float hsum[16*96];
    __shared__ float z1[16*16];
    __shared__ float z2[16*8];

    const int tid=threadIdx.x;
    const int b=blockIdx.x, row0=b*NB;
    f16* strip = ws_strip + (size_t)b*T_STEPS*ST_T;
    const int GH = 384*96;

    layer_run<24, true,  true,  false, false>(x, strip, W_ih0,             W_hh,        b_ih,          b_hh,          sh,sl,gbuf,hsum,row0);
    __syncthreads();
    layer_run<96, false, true,  true,  false>(nullptr, strip, W_ih_rest,        W_hh+1*GH, b_ih+1*384, b_hh+1*384, sh,sl,gbuf,hsum,row0);
    __syncthreads();
    layer_run<96, false, true,  false, false>(nullptr, strip, W_ih_rest+1*GH, W_hh+2*GH, b_ih+2*384, b_hh+2*384, sh,sl,gbuf,hsum,row0);
    __syncthreads();
    layer_run<96, false, false, false, true >(nullptr, strip, W_ih_rest+2*GH, W_hh+3*GH, b_ih+3*384, b_hh+3*384, sh,sl,gbuf,hsum,row0);
    __syncthreads();

    // ---- fused head: relu(hsum) -> fc1 -> relu -> fc2 -> relu -> fc3 ----
    if (tid<256){
        int r=tid>>4, jj=tid&15;
        float a=fc1_b[jj];
        for (int uu=0;uu<96;++uu) a+=fc1_w[jj*96+uu]*fmaxf(hsum[r*96+uu],0.f);
        z1[r*16+jj]=fmaxf(a,0.f);
    }
    __syncthreads();
    if (tid<128){
        int r=tid>>3, jj=tid&7;
        float a=fc2_b[jj];
#pragma unroll
        for (int uu=0;uu<16;++uu) a+=fc2_w[jj*16+uu]*z1[r*16+uu];
        z2[r*8+jj]=fmaxf(a,0.f);
    }
    __syncthreads();
    if (tid<16){
        float a=fc3_b[0];
#pragma unroll
        for (int uu=0;uu<8;++uu) a+=fc3_w[uu]*z2[tid*8+uu];
        out[row0+tid]=a;
    }
}

extern "C" void kernel_launch(void* const* d_in, const int* in_sizes, int n_in,
                              void* d_out, int out_size, void* d_ws, size_t ws_size,
                              hipStream_t stream) {
    const float* x         = (const float*)d_in[0];
    const float* W_ih0     = (const float*)d_in[1];
    const float* W_ih_rest = (const float*)d_in[2];
    const float* W_hh      = (const float*)d_in[3];
    const float* b_ih      = (const float*)d_in[4];
    const float* b_hh      = (const float*)d_in[5];
    const float* fc1_w     = (const float*)d_in[6];
    const float* fc1_b     = (const float*)d_in[7];
    const float* fc2_w     = (const float*)d_in[8];
    const float* fc2_b     = (const float*)d_in[9];
    const float* fc3_w     = (const float*)d_in[10];
    const float* fc3_b     = (const float*)d_in[11];
    float* out = (float*)d_out;

    const size_t WS = (size_t)NBLK * T_STEPS * ST_T * sizeof(f16);  // ~100.7 MB
    if (ws_size < WS) {
        hipMemsetAsync(d_out, 0, (size_t)out_size * sizeof(float), stream);
        return;
    }

    lstm_all<<<dim3(NBLK), dim3(NTH), 0, stream>>>(
        x, W_ih0, W_ih_rest, W_hh, b_ih, b_hh,
        fc1_w, fc1_b, fc2_w, fc2_b, fc3_w, fc3_b,
        (f16*)d_ws, out);
}

// Round 19
// 581.841 us; speedup vs baseline: 1.4830x; 1.0531x over previous
//
#include <hip/hip_runtime.h>
#include <math.h>

typedef _Float16 f16;
typedef _Float16 f16x8 __attribute__((ext_vector_type(8)));
typedef float f32x4 __attribute__((ext_vector_type(4)));
typedef float f32x2 __attribute__((ext_vector_type(2)));

#define B_TOTAL 4096
#define T_STEPS 128
#define H 96
#define NB 16               // batch rows per block
#define NTH 768             // 12 waves = 3 waves/SIMD
#define NBLK (B_TOTAL/NB)   // 256 blocks = 1 per CU
#define GUP 97              // gbuf unit stride (pad -> <=2-way conflicts)
#define ST_T (NB*H)         // f16 per strip timestep slot = 1536
#define LOG2E 1.44269504088896f

// R19: exp2-folded nonlinearities (weights pre-scaled by log2e / 2log2e at
// load -> bare v_exp_f32, no per-exp v_mul) + gates ACTIVATED in the MFMA
// phase (trans/VALU co-issues with other waves' MFMAs; post-barrier EW phase
// shrinks to c/h update only).
__device__ __forceinline__ float sig2(float vp){   // vp = v * log2e
    return __builtin_amdgcn_rcpf(1.f + __builtin_amdgcn_exp2f(-vp));
}
__device__ __forceinline__ float tanh2(float vpp){ // vpp = v * 2log2e
    return 1.f - 2.f*__builtin_amdgcn_rcpf(__builtin_amdgcn_exp2f(vpp) + 1.f);
}
__device__ __forceinline__ float tanh_c(float c){  // c in true scale
    return tanh2(c * (2.f*LOG2E));
}

// LDS-only barrier: no vmcnt(0) drain (R13-proven safe here).
__device__ __forceinline__ void lds_barrier(){
    __builtin_amdgcn_sched_barrier(0);
    asm volatile("s_waitcnt lgkmcnt(0)" ::: "memory");
    __builtin_amdgcn_s_barrier();
    __builtin_amdgcn_sched_barrier(0);
}

// One LSTM layer over all T for this block's 16 rows (R17/R18 structure).
template<int F, bool IS_L0, bool HAS_YSOUT, bool WRITE_HSUM, bool ADD_HSUM>
__device__ __forceinline__ void layer_run(
    const float* __restrict__ x32, f16* __restrict__ strip,
    const float* __restrict__ Wi, const float* __restrict__ Wh,
    const float* __restrict__ bi, const float* __restrict__ bh,
    f16* sh, f16* sl, float* gbuf, float* hsum, int row0)
{
    constexpr int  KS   = (F + H + 31)/32;   // 4 (F=24) or 6 (F=96)
    constexpr int  KP   = KS*32;
    constexpr int  KPB  = KP*2;
    constexpr bool HAS_LO = IS_L0;
    constexpr int  BUF  = 16*KP;

    const int tid=threadIdx.x, lane=tid&63, w=tid>>6;
    const int j15=lane&15, g4=lane>>4;
    const int g=w>>1, q0=(w&1)*2;
    const int u=16*g+j15;
    const int eu=tid>>3, er0=(tid&7)*2;
    const int sr=tid/48, su=(tid-sr*48)*2;
    const int ysrd_off = sr*KPB + (((F+su)*2) ^ ((sr&7)<<4));

    for (int i=tid;i<2*BUF;i+=NTH) sh[i]=(f16)0.f;
    if constexpr (HAS_LO)
        for (int i=tid;i<2*BUF;i+=NTH) sl[i]=(f16)0.f;

    // weight B-frags, PRE-SCALED: gate g (q=2) by 2log2e, others by log2e,
    // so nonlinearities use bare exp2. lane holds W[j=96*(q0+qq)+u][k]
    f16x8 Bf[2][KS];
    float scl[2];
#pragma unroll
    for (int qq=0;qq<2;++qq) scl[qq] = (q0+qq==2) ? 2.f*LOG2E : LOG2E;
#pragma unroll
    for (int qq=0;qq<2;++qq){
        const int j=96*(q0+qq)+u;
#pragma unroll
        for (int s=0;s<KS;++s){
            f16x8 f;
#pragma unroll
            for (int e=0;e<8;++e){
                int k=32*s+8*g4+e;
                float v=0.f;
                if (k<F)        v=Wi[(size_t)j*F+k];
                else if (k-F<H) v=Wh[(size_t)j*H+(k-F)];
                f[e]=(f16)(v*scl[qq]);
            }
            Bf[qq][s]=f;
        }
    }
    float bq[2];
#pragma unroll
    for (int qq=0;qq<2;++qq)
        bq[qq]=(bi[96*(q0+qq)+u]+bh[96*(q0+qq)+u])*scl[qq];

    float c2[2]={0.f,0.f};

    // strip role pointers — all collapse to +tid on the block-private strip
    unsigned*       ysst = (unsigned*)strip + tid;           // store slot t=0
    const unsigned* yld  = (const unsigned*)strip + (ST_T/2) + tid;  // load t=1
    const int yr=(tid*2)/H, yk=(tid*2)-yr*H;
    const int yoff = yr*KPB + ((yk*2)^((yr&7)<<4));

    const int xr=tid/24, xk=tid-xr*24;
    const bool xact = IS_L0 && (tid < NB*24);
    const float* xbase = xact ? x32 + (size_t)(row0+xr)*(T_STEPS*24) + xk : nullptr;
    const int xoff = xr*KPB + ((xk*2)^((xr&7)<<4));

    // stage t=0 into buffer 0
    if constexpr (IS_L0){
        if (xact){
            float v=xbase[0];
            f16 vh=(f16)v, vl=(f16)(v-(float)vh);
            *(f16*)((char*)sh+xoff)=vh; *(f16*)((char*)sl+xoff)=vl;
        }
    } else {
        unsigned v = *((const unsigned*)strip + tid);
        *(unsigned*)((char*)sh+yoff)=v;
    }
    __syncthreads();

    // 2-deep prefetch prologue: yvA <- strip[1]
    unsigned yvA=0u;
    if constexpr (!IS_L0){ yvA = *yld; yld += ST_T/2; }

    const int aswz=(j15&7)<<4;
    const int abase=j15*KPB;
    int gw[4];
#pragma unroll
    for (int r=0;r<4;++r) gw[r]=(((4*g4+r)*GUP+u)*4+q0)*4;
    int grd[2], nho[2];
#pragma unroll
    for (int s2=0;s2<2;++s2){
        grd[s2]=((er0+s2)*GUP+eu)*16;
        nho[s2]=(er0+s2)*KPB + (((F+eu)*2)^(((er0+s2)&7)<<4));
    }

#pragma unroll 1
    for (int t=0;t<T_STEPS;++t){
        const int cur=t&1, nxt=cur^1;
        const char* chb=(const char*)(sh+cur*BUF);
        const char* clb=HAS_LO ? (const char*)(sl+cur*BUF) : nullptr;
        char*       nhb=(char*)(sh+nxt*BUF);
        char*       nlb=HAS_LO ? (char*)(sl+nxt*BUF) : nullptr;

        float xv=0.f; unsigned yvB=0u;
        if constexpr (IS_L0){
            if (xact && t+1<T_STEPS) xv = xbase[(size_t)(t+1)*24];
        } else {
            if (t+2<T_STEPS){ yvB = *yld; yld += ST_T/2; }
        }
        __builtin_amdgcn_sched_barrier(0);

        unsigned hbits=0u;
        if (HAS_YSOUT && t>0) hbits = *(const unsigned*)(chb + ysrd_off);

        // ---- MFMA phase: 2 gates x parity-split chains ----
        f32x4 acc[2][2];
#pragma unroll
        for (int qq=0;qq<2;++qq){
            f32x4 a={bq[qq],bq[qq],bq[qq],bq[qq]}; acc[qq][0]=a;
            f32x4 z={0.f,0.f,0.f,0.f};              acc[qq][1]=z;
        }
#pragma unroll
        for (int s=0;s<KS;++s){
            int kb=((s*64+g4*16)^aswz);
            f16x8 ah=*(const f16x8*)(chb+abase+kb);
            if (s&1){
                acc[0][1]=__builtin_amdgcn_mfma_f32_16x16x32_f16(ah,Bf[0][s],acc[0][1],0,0,0);
                acc[1][1]=__builtin_amdgcn_mfma_f32_16x16x32_f16(ah,Bf[1][s],acc[1][1],0,0,0);
            } else {
                acc[0][0]=__builtin_amdgcn_mfma_f32_16x16x32_f16(ah,Bf[0][s],acc[0][0],0,0,0);
                acc[1][0]=__builtin_amdgcn_mfma_f32_16x16x32_f16(ah,Bf[1][s],acc[1][0],0,0,0);
            }
        }
        if constexpr (HAS_LO){
            int kb=((g4*16)^aswz);
            f16x8 al=*(const f16x8*)(clb+abase+kb);
            acc[0][1]=__builtin_amdgcn_mfma_f32_16x16x32_f16(al,Bf[0][0],acc[0][1],0,0,0);
            acc[1][1]=__builtin_amdgcn_mfma_f32_16x16x32_f16(al,Bf[1][0],acc[1][1],0,0,0);
        }
        // activate gates HERE (co-issues with other waves' MFMAs) and write
        // activated f32 values to gbuf. Wave-uniform branch on q0:
        //   q0==0 -> gates i,f (both sigmoid); q0==2 -> gates g (tanh), o (sig)
#pragma unroll
        for (int r=0;r<4;++r){
            float v0=acc[0][0][r]+acc[0][1][r];
            float v1=acc[1][0][r]+acc[1][1][r];
            float a0 = (q0==0) ? sig2(v0) : tanh2(v0);
            float a1 = sig2(v1);
            f32x2 p={a0,a1};
            *(f32x2*)((char*)gbuf + gw[r]) = p;
        }
        lds_barrier();

        if (HAS_YSOUT && t>0){ *ysst = hbits; ysst += ST_T/2; }

        // ---- elementwise: 2 cells, 1 ds_read_b128 each; gates pre-activated
#pragma unroll
        for (int s2=0;s2<2;++s2){
            f32x4 gv4 = *(const f32x4*)((const char*)gbuf + grd[s2]);
            float c = gv4[1]*c2[s2] + gv4[0]*gv4[2];   // f*c + i*g
            c2[s2]=c;
            float h = gv4[3]*tanh_c(c);                // o * tanh(c)
            *(f16*)(nhb + nho[s2]) = (f16)h;
            if constexpr (WRITE_HSUM){ if (t==T_STEPS-1) hsum[(er0+s2)*96+eu]=h; }
            if constexpr (ADD_HSUM)  { if (t==T_STEPS-1) hsum[(er0+s2)*96+eu]+=h; }
        }
        if (t+1<T_STEPS){
            if constexpr (IS_L0){
                if (xact){
                    f16 vh=(f16)xv, vl=(f16)(xv-(float)vh);
                    *(f16*)(nhb+xoff)=vh; *(f16*)(nlb+xoff)=vl;
                }
            } else {
                *(unsigned*)(nhb+yoff)=yvA;
            }
        }
        lds_barrier();
        yvA = yvB;
    }
    // final strip store: h(T-1) sits in buf[0] (T even)
    if constexpr (HAS_YSOUT){
        unsigned hbits = *(const unsigned*)((const char*)sh + ysrd_off);
        asm volatile("s_waitcnt lgkmcnt(0)" ::: "memory");
        *ysst = hbits;
    }
}

__global__ __launch_bounds__(NTH, 1)
void lstm_all(const float* __restrict__ x,
              const float* __restrict__ W_ih0,
              const float* __restrict__ W_ih_rest,
              const float* __restrict__ W_hh,
              const float* __restrict__ b_ih,
              const float* __restrict__ b_hh,
              const float* __restrict__ fc1_w, const float* __restrict__ fc1_b,
              const float* __restrict__ fc2_w, const float* __restrict__ fc2_b,
              const float* __restrict__ fc3_w, const float* __restrict__ fc3_b,
              f16* __restrict__ ws_strip, float* __restrict__ out)
{
    __shared__ f16 sh[2*16*192];           // act hi (max KP=192), double-buffered
    __shared__ f16 sl[2*16*128];           // act lo (L0 only, KP=128)
    __shared__ float gbuf[16*GUP*4];
    __shared__ float hsum[16*96];
    __shared__ float z1[16*16];
    __shared__ float z2[16*8];

    const int tid=threadIdx.x;
    const int b=blockIdx.x, row0=b*NB;
    f16* strip = ws_strip + (size_t)b*T_STEPS*ST_T;
    const int GH = 384*96;

    layer_run<24, true,  true,  false, false>(x, strip, W_ih0,             W_hh,        b_ih,          b_hh,          sh,sl,gbuf,hsum,row0);
    __syncthreads();
    layer_run<96, false, true,  true,  false>(nullptr, strip, W_ih_rest,        W_hh+1*GH, b_ih+1*384, b_hh+1*384, sh,sl,gbuf,hsum,row0);
    __syncthreads();
    layer_run<96, false, true,  false, false>(nullptr, strip, W_ih_rest+1*GH, W_hh+2*GH, b_ih+2*384, b_hh+2*384, sh,sl,gbuf,hsum,row0);
    __syncthreads();
    layer_run<96, false, false, false, true >(nullptr, strip, W_ih_rest+2*GH, W_hh+3*GH, b_ih+3*384, b_hh+3*384, sh,sl,gbuf,hsum,row0);
    __syncthreads();

    // ---- fused head: relu(hsum) -> fc1 -> relu -> fc2 -> relu -> fc3 ----
    if (tid<256){
        int r=tid>>4, jj=tid&15;
        float a=fc1_b[jj];
        for (int uu=0;uu<96;++uu) a+=fc1_w[jj*96+uu]*fmaxf(hsum[r*96+uu],0.f);
        z1[r*16+jj]=fmaxf(a,0.f);
    }
    __syncthreads();
    if (tid<128){
        int r=tid>>3, jj=tid&7;
        float a=fc2_b[jj];
#pragma unroll
        for (int uu=0;uu<16;++uu) a+=fc2_w[jj*16+uu]*z1[r*16+uu];
        z2[r*8+jj]=fmaxf(a,0.f);
    }
    __syncthreads();
    if (tid<16){
        float a=fc3_b[0];
#pragma unroll
        for (int uu=0;uu<8;++uu) a+=fc3_w[uu]*z2[tid*8+uu];
        out[row0+tid]=a;
    }
}

extern "C" void kernel_launch(void* const* d_in, const int* in_sizes, int n_in,
                              void* d_out, int out_size, void* d_ws, size_t ws_size,
                              hipStream_t stream) {
    const float* x         = (const float*)d_in[0];
    const float* W_ih0     = (const float*)d_in[1];
    const float* W_ih_rest = (const float*)d_in[2];
    const float* W_hh      = (const float*)d_in[3];
    const float* b_ih      = (const float*)d_in[4];
    const float* b_hh      = (const float*)d_in[5];
    const float* fc1_w     = (const float*)d_in[6];
    const float* fc1_b     = (const float*)d_in[7];
    const float* fc2_w     = (const float*)d_in[8];
    const float* fc2_b     = (const float*)d_in[9];
    const float* fc3_w     = (const float*)d_in[10];
    const float* fc3_b     = (const float*)d_in[11];
    float* out = (float*)d_out;

    const size_t WS = (size_t)NBLK * T_STEPS * ST_T * sizeof(f16);  // ~100.7 MB
    if (ws_size < WS) {
        hipMemsetAsync(d_out, 0, (size_t)out_size * sizeof(float), stream);
        return;
    }

    lstm_all<<<dim3(NBLK), dim3(NTH), 0, stream>>>(
        x, W_ih0, W_ih_rest, W_hh, b_ih, b_hh,
        fc1_w, fc1_b, fc2_w, fc2_b, fc3_w, fc3_b,
        (f16*)d_ws, out);
}

// Round 20
// 568.557 us; speedup vs baseline: 1.5176x; 1.0234x over previous
//
#include <hip/hip_runtime.h>
#include <math.h>

typedef _Float16 f16;
typedef _Float16 f16x8 __attribute__((ext_vector_type(8)));
typedef float f32x4 __attribute__((ext_vector_type(4)));
typedef float f32x2 __attribute__((ext_vector_type(2)));

#define B_TOTAL 4096
#define T_STEPS 128
#define H 96
#define NB 16               // batch rows per block
#define NTH 768             // 12 waves = 3 waves/SIMD
#define NBLK (B_TOTAL/NB)   // 256 blocks = 1 per CU
#define ST_T (NB*H)         // f16 per strip timestep slot = 1536
#define LOG2E 1.44269504088896f

// R19 nonlinearities: exp2-folded (weights pre-scaled), v_rcp.
__device__ __forceinline__ float sig2(float vp){   // vp = v * log2e
    return __builtin_amdgcn_rcpf(1.f + __builtin_amdgcn_exp2f(-vp));
}
__device__ __forceinline__ float tanh2(float vpp){ // vpp = v * 2log2e
    return 1.f - 2.f*__builtin_amdgcn_rcpf(__builtin_amdgcn_exp2f(vpp) + 1.f);
}
__device__ __forceinline__ float tanh_c(float c){  // c in true scale
    return tanh2(c * (2.f*LOG2E));
}

// LDS-only barrier: no vmcnt(0) drain (R13-proven safe here).
__device__ __forceinline__ void lds_barrier(){
    __builtin_amdgcn_sched_barrier(0);
    asm volatile("s_waitcnt lgkmcnt(0)" ::: "memory");
    __builtin_amdgcn_s_barrier();
    __builtin_amdgcn_sched_barrier(0);
}

// R20: conflict-free gbuf. Layout [cell][4 gates] f32, cell = row*96+u,
// 16B/cell. EW thread tid owns cells {tid, tid+768} -> ds_read_b128 at
// tid*16 = lane-linear (canonical conflict-free). MFMA b64 write bank =
// 4*(j15%8)+q0 -> 2-way (free). Replaces the old GUP=97 layout whose
// x4-dword stride quantized banks to multiples of 4 (8-way both sides,
// 54M conflict-cycles/dispatch = ~13% of cycles).
template<int F, bool IS_L0, bool HAS_YSOUT, bool WRITE_HSUM, bool ADD_HSUM>
__device__ __forceinline__ void layer_run(
    const float* __restrict__ x32, f16* __restrict__ strip,
    const float* __restrict__ Wi, const float* __restrict__ Wh,
    const float* __restrict__ bi, const float* __restrict__ bh,
    f16* sh, f16* sl, float* gbuf, float* hsum, int row0)
{
    constexpr int  KS   = (F + H + 31)/32;   // 4 (F=24) or 6 (F=96)
    constexpr int  KP   = KS*32;
    constexpr int  KPB  = KP*2;
    constexpr bool HAS_LO = IS_L0;
    constexpr int  BUF  = 16*KP;

    const int tid=threadIdx.x, lane=tid&63, w=tid>>6;
    const int j15=lane&15, g4=lane>>4;
    const int g=w>>1, q0=(w&1)*2;
    const int u=16*g+j15;
    // EW role: cells tid (row_, u_) and tid+768 (row_+8, u_)
    const int row_=tid/96, u_=tid-96*row_;
    const int sr=tid/48, su=(tid-sr*48)*2;
    const int ysrd_off = sr*KPB + (((F+su)*2) ^ ((sr&7)<<4));

    for (int i=tid;i<2*BUF;i+=NTH) sh[i]=(f16)0.f;
    if constexpr (HAS_LO)
        for (int i=tid;i<2*BUF;i+=NTH) sl[i]=(f16)0.f;

    // weight B-frags, PRE-SCALED (gate g by 2log2e, others log2e)
    f16x8 Bf[2][KS];
    float scl[2];
#pragma unroll
    for (int qq=0;qq<2;++qq) scl[qq] = (q0+qq==2) ? 2.f*LOG2E : LOG2E;
#pragma unroll
    for (int qq=0;qq<2;++qq){
        const int j=96*(q0+qq)+u;
#pragma unroll
        for (int s=0;s<KS;++s){
            f16x8 f;
#pragma unroll
            for (int e=0;e<8;++e){
                int k=32*s+8*g4+e;
                float v=0.f;
                if (k<F)        v=Wi[(size_t)j*F+k];
                else if (k-F<H) v=Wh[(size_t)j*H+(k-F)];
                f[e]=(f16)(v*scl[qq]);
            }
            Bf[qq][s]=f;
        }
    }
    float bq[2];
#pragma unroll
    for (int qq=0;qq<2;++qq)
        bq[qq]=(bi[96*(q0+qq)+u]+bh[96*(q0+qq)+u])*scl[qq];

    float c2[2]={0.f,0.f};

    // strip role pointers — all collapse to +tid on the block-private strip
    unsigned*       ysst = (unsigned*)strip + tid;           // store slot t=0
    const unsigned* yld  = (const unsigned*)strip + (ST_T/2) + tid;  // load t=1
    const int yr=(tid*2)/H, yk=(tid*2)-yr*H;
    const int yoff = yr*KPB + ((yk*2)^((yr&7)<<4));

    const int xr=tid/24, xk=tid-xr*24;
    const bool xact = IS_L0 && (tid < NB*24);
    const float* xbase = xact ? x32 + (size_t)(row0+xr)*(T_STEPS*24) + xk : nullptr;
    const int xoff = xr*KPB + ((xk*2)^((xr&7)<<4));

    // stage t=0 into buffer 0
    if constexpr (IS_L0){
        if (xact){
            float v=xbase[0];
            f16 vh=(f16)v, vl=(f16)(v-(float)vh);
            *(f16*)((char*)sh+xoff)=vh; *(f16*)((char*)sl+xoff)=vl;
        }
    } else {
        unsigned v = *((const unsigned*)strip + tid);
        *(unsigned*)((char*)sh+yoff)=v;
    }
    __syncthreads();

    // 2-deep prefetch prologue: yvA <- strip[1]
    unsigned yvA=0u;
    if constexpr (!IS_L0){ yvA = *yld; yld += ST_T/2; }

    const int aswz=(j15&7)<<4;
    const int abase=j15*KPB;
    // gbuf offsets (bytes): write (row=4g4+r, u) gate-pair q0; read cells tid/tid+768
    int gw[4];
#pragma unroll
    for (int r=0;r<4;++r) gw[r]=((4*g4+r)*96 + u)*16 + q0*4;
    int grd[2], nho[2], hsi[2];
#pragma unroll
    for (int s2=0;s2<2;++s2){
        grd[s2]=(tid + s2*768)*16;
        int row=row_+8*s2;
        nho[s2]=row*KPB + (((F+u_)*2)^((row&7)<<4));
        hsi[s2]=row*96+u_;
    }

#pragma unroll 1
    for (int t=0;t<T_STEPS;++t){
        const int cur=t&1, nxt=cur^1;
        const char* chb=(const char*)(sh+cur*BUF);
        const char* clb=HAS_LO ? (const char*)(sl+cur*BUF) : nullptr;
        char*       nhb=(char*)(sh+nxt*BUF);
        char*       nlb=HAS_LO ? (char*)(sl+nxt*BUF) : nullptr;

        float xv=0.f; unsigned yvB=0u;
        if constexpr (IS_L0){
            if (xact && t+1<T_STEPS) xv = xbase[(size_t)(t+1)*24];
        } else {
            if (t+2<T_STEPS){ yvB = *yld; yld += ST_T/2; }
        }
        __builtin_amdgcn_sched_barrier(0);

        unsigned hbits=0u;
        if (HAS_YSOUT && t>0) hbits = *(const unsigned*)(chb + ysrd_off);

        // ---- MFMA phase: 2 gates x parity-split chains ----
        f32x4 acc[2][2];
#pragma unroll
        for (int qq=0;qq<2;++qq){
            f32x4 a={bq[qq],bq[qq],bq[qq],bq[qq]}; acc[qq][0]=a;
            f32x4 z={0.f,0.f,0.f,0.f};              acc[qq][1]=z;
        }
#pragma unroll
        for (int s=0;s<KS;++s){
            int kb=((s*64+g4*16)^aswz);
            f16x8 ah=*(const f16x8*)(chb+abase+kb);
            if (s&1){
                acc[0][1]=__builtin_amdgcn_mfma_f32_16x16x32_f16(ah,Bf[0][s],acc[0][1],0,0,0);
                acc[1][1]=__builtin_amdgcn_mfma_f32_16x16x32_f16(ah,Bf[1][s],acc[1][1],0,0,0);
            } else {
                acc[0][0]=__builtin_amdgcn_mfma_f32_16x16x32_f16(ah,Bf[0][s],acc[0][0],0,0,0);
                acc[1][0]=__builtin_amdgcn_mfma_f32_16x16x32_f16(ah,Bf[1][s],acc[1][0],0,0,0);
            }
        }
        if constexpr (HAS_LO){
            int kb=((g4*16)^aswz);
            f16x8 al=*(const f16x8*)(clb+abase+kb);
            acc[0][1]=__builtin_amdgcn_mfma_f32_16x16x32_f16(al,Bf[0][0],acc[0][1],0,0,0);
            acc[1][1]=__builtin_amdgcn_mfma_f32_16x16x32_f16(al,Bf[1][0],acc[1][1],0,0,0);
        }
        // activate gates (co-issues with other waves' MFMAs), write to gbuf.
        // q0==0 -> i,f (sig,sig); q0==2 -> g (tanh), o (sig)
#pragma unroll
        for (int r=0;r<4;++r){
            float v0=acc[0][0][r]+acc[0][1][r];
            float v1=acc[1][0][r]+acc[1][1][r];
            float a0 = (q0==0) ? sig2(v0) : tanh2(v0);
            float a1 = sig2(v1);
            f32x2 p={a0,a1};
            *(f32x2*)((char*)gbuf + gw[r]) = p;
        }
        lds_barrier();

        if (HAS_YSOUT && t>0){ *ysst = hbits; ysst += ST_T/2; }

        // ---- elementwise: 2 cells, lane-linear ds_read_b128 ----
#pragma unroll
        for (int s2=0;s2<2;++s2){
            f32x4 gv4 = *(const f32x4*)((const char*)gbuf + grd[s2]);
            float c = gv4[1]*c2[s2] + gv4[0]*gv4[2];   // f*c + i*g
            c2[s2]=c;
            float h = gv4[3]*tanh_c(c);                // o * tanh(c)
            *(f16*)(nhb + nho[s2]) = (f16)h;
            if constexpr (WRITE_HSUM){ if (t==T_STEPS-1) hsum[hsi[s2]]=h; }
            if constexpr (ADD_HSUM)  { if (t==T_STEPS-1) hsum[hsi[s2]]+=h; }
        }
        if (t+1<T_STEPS){
            if constexpr (IS_L0){
                if (xact){
                    f16 vh=(f16)xv, vl=(f16)(xv-(float)vh);
                    *(f16*)(nhb+xoff)=vh; *(f16*)(nlb+xoff)=vl;
                }
            } else {
                *(unsigned*)(nhb+yoff)=yvA;
            }
        }
        lds_barrier();
        yvA = yvB;
    }
    // final strip store: h(T-1) sits in buf[0] (T even)
    if constexpr (HAS_YSOUT){
        unsigned hbits = *(const unsigned*)((const char*)sh + ysrd_off);
        asm volatile("s_waitcnt lgkmcnt(0)" ::: "memory");
        *ysst = hbits;
    }
}

__global__ __launch_bounds__(NTH, 1)
void lstm_all(const float* __restrict__ x,
              const float* __restrict__ W_ih0,
              const float* __restrict__ W_ih_rest,
              const float* __restrict__ W_hh,
              const float* __restrict__ b_ih,
              const float* __restrict__ b_hh,
              const float* __restrict__ fc1_w, const float* __restrict__ fc1_b,
              const float* __restrict__ fc2_w, const float* __restrict__ fc2_b,
              const float* __restrict__ fc3_w, const float* __restrict__ fc3_b,
              f16* __restrict__ ws_strip, float* __restrict__ out)
{
    __shared__ f16 sh[2*16*192];           // act hi (max KP=192), double-buffered
    __shared__ f16 sl[2*16*128];           // act lo (L0 only, KP=128)
    __shared__ float gbuf[1536*4];         // [cell][gate] 16B/cell, conflict-free
    __shared__ float hsum[16*96];
    __shared__ float z1[16*16];
    __shared__ float z2[16*8];

    const int tid=threadIdx.x;
    const int b=blockIdx.x, row0=b*NB;
    f16* strip = ws_strip + (size_t)b*T_STEPS*ST_T;
    const int GH = 384*96;

    layer_run<24, true,  true,  false, false>(x, strip, W_ih0,             W_hh,        b_ih,          b_hh,          sh,sl,gbuf,hsum,row0);
    __syncthreads();
    layer_run<96, false, true,  true,  false>(nullptr, strip, W_ih_rest,        W_hh+1*GH, b_ih+1*384, b_hh+1*384, sh,sl,gbuf,hsum,row0);
    __syncthreads();
    layer_run<96, false, true,  false, false>(nullptr, strip, W_ih_rest+1*GH, W_hh+2*GH, b_ih+2*384, b_hh+2*384, sh,sl,gbuf,hsum,row0);
    __syncthreads();
    layer_run<96, false, false, false, true >(nullptr, strip, W_ih_rest+2*GH, W_hh+3*GH, b_ih+3*384, b_hh+3*384, sh,sl,gbuf,hsum,row0);
    __syncthreads();

    // ---- fused head: relu(hsum) -> fc1 -> relu -> fc2 -> relu -> fc3 ----
    if (tid<256){
        int r=tid>>4, jj=tid&15;
        float a=fc1_b[jj];
        for (int uu=0;uu<96;++uu) a+=fc1_w[jj*96+uu]*fmaxf(hsum[r*96+uu],0.f);
        z1[r*16+jj]=fmaxf(a,0.f);
    }
    __syncthreads();
    if (tid<128){
        int r=tid>>3, jj=tid&7;
        float a=fc2_b[jj];
#pragma unroll
        for (int uu=0;uu<16;++uu) a+=fc2_w[jj*16+uu]*z1[r*16+uu];
        z2[r*8+jj]=fmaxf(a,0.f);
    }
    __syncthreads();
    if (tid<16){
        float a=fc3_b[0];
#pragma unroll
        for (int uu=0;uu<8;++uu) a+=fc3_w[uu]*z2[tid*8+uu];
        out[row0+tid]=a;
    }
}

extern "C" void kernel_launch(void* const* d_in, const int* in_sizes, int n_in,
                              void* d_out, int out_size, void* d_ws, size_t ws_size,
                              hipStream_t stream) {
    const float* x         = (const float*)d_in[0];
    const float* W_ih0     = (const float*)d_in[1];
    const float* W_ih_rest = (const float*)d_in[2];
    const float* W_hh      = (const float*)d_in[3];
    const float* b_ih      = (const float*)d_in[4];
    const float* b_hh      = (const float*)d_in[5];
    const float* fc1_w     = (const float*)d_in[6];
    const float* fc1_b     = (const float*)d_in[7];
    const float* fc2_w     = (const float*)d_in[8];
    const float* fc2_b     = (const float*)d_in[9];
    const float* fc3_w     = (const float*)d_in[10];
    const float* fc3_b     = (const float*)d_in[11];
    float* out = (float*)d_out;

    const size_t WS = (size_t)NBLK * T_STEPS * ST_T * sizeof(f16);  // ~100.7 MB
    if (ws_size < WS) {
        hipMemsetAsync(d_out, 0, (size_t)out_size * sizeof(float), stream);
        return;
    }

    lstm_all<<<dim3(NBLK), dim3(NTH), 0, stream>>>(
        x, W_ih0, W_ih_rest, W_hh, b_ih, b_hh,
        fc1_w, fc1_b, fc2_w, fc2_b, fc3_w, fc3_b,
        (f16*)d_ws, out);
}

// Round 21
// 561.515 us; speedup vs baseline: 1.5367x; 1.0125x over previous
//
#include <hip/hip_runtime.h>
#include <math.h>

typedef _Float16 f16;
typedef _Float16 f16x8 __attribute__((ext_vector_type(8)));
typedef float f32x4 __attribute__((ext_vector_type(4)));
typedef float f32x2 __attribute__((ext_vector_type(2)));

#define B_TOTAL 4096
#define T_STEPS 128
#define H 96
#define NB 16               // batch rows per block
#define NTH 768             // 12 waves = 3 waves/SIMD
#define NBLK (B_TOTAL/NB)   // 256 blocks = 1 per CU
#define ST_T (NB*H)         // f16 per strip timestep slot = 1536
#define LOG2E 1.44269504088896f

// exp2-folded nonlinearities (R19), v_rcp (R18).
__device__ __forceinline__ float sig2(float vp){   // vp = v * log2e
    return __builtin_amdgcn_rcpf(1.f + __builtin_amdgcn_exp2f(-vp));
}
__device__ __forceinline__ float tanh2(float vpp){ // vpp = v * 2log2e
    return 1.f - 2.f*__builtin_amdgcn_rcpf(__builtin_amdgcn_exp2f(vpp) + 1.f);
}
__device__ __forceinline__ float tanh_c(float c){  // c in true scale
    return tanh2(c * (2.f*LOG2E));
}

// LDS-only barrier: no vmcnt(0) drain (R13-proven safe here).
__device__ __forceinline__ void lds_barrier(){
    __builtin_amdgcn_sched_barrier(0);
    asm volatile("s_waitcnt lgkmcnt(0)" ::: "memory");
    __builtin_amdgcn_s_barrier();
    __builtin_amdgcn_sched_barrier(0);
}

// R21: gate re-pairing kills the gbuf round trip (LDS-throughput model:
// step was ~1800cy of LDS pipe vs 700 MFMA). Wave A owns gates {i,g}:
// writes only p = sig(i)*tanh(g) (lane-aligned f32x2 pair, same C-tile lane
// map as B). Wave B owns {f,o}: keeps c REGISTER-RESIDENT, c = sig(f)*c + p,
// h = sig(o)*tanh(c), writes h to the act buffer. The 768-thread EW phase
// and the 24KB gbuf disappear. B's sig(f)/sig(o) computed pre-barrier.
template<int F, bool IS_L0, bool HAS_YSOUT, bool WRITE_HSUM, bool ADD_HSUM>
__device__ __forceinline__ void layer_run(
    const float* __restrict__ x32, f16* __restrict__ strip,
    const float* __restrict__ Wi, const float* __restrict__ Wh,
    const float* __restrict__ bi, const float* __restrict__ bh,
    f16* sh, f16* sl, float* p_lds, float* hsum, int row0)
{
    constexpr int  KS   = (F + H + 31)/32;   // 4 (F=24) or 6 (F=96)
    constexpr int  KP   = KS*32;
    constexpr int  KPB  = KP*2;
    constexpr bool HAS_LO = IS_L0;
    constexpr int  BUF  = 16*KP;

    const int tid=threadIdx.x, lane=tid&63, w=tid>>6;
    const int j15=lane&15, g4=lane>>4;
    const int g=w>>1;                        // unit group 0..5
    const int qsel=w&1;                      // 0: A={i,g}; 1: B={f,o}
    const int u=16*g+j15;
    const int sr=tid/48, su=(tid-sr*48)*2;
    const int ysrd_off = sr*KPB + (((F+su)*2) ^ ((sr&7)<<4));

    for (int i=tid;i<2*BUF;i+=NTH) sh[i]=(f16)0.f;
    if constexpr (HAS_LO)
        for (int i=tid;i<2*BUF;i+=NTH) sl[i]=(f16)0.f;

    // weight B-frags, PRE-SCALED. Gates: A -> {0 (i), 2 (g)}, B -> {1 (f), 3 (o)}
    f16x8 Bf[2][KS];
    float scl[2];
#pragma unroll
    for (int qq=0;qq<2;++qq){
        int qg = qsel + 2*qq;
        scl[qq] = (qg==2) ? 2.f*LOG2E : LOG2E;
    }
#pragma unroll
    for (int qq=0;qq<2;++qq){
        const int j=96*(qsel+2*qq)+u;
#pragma unroll
        for (int s=0;s<KS;++s){
            f16x8 f;
#pragma unroll
            for (int e=0;e<8;++e){
                int k=32*s+8*g4+e;
                float v=0.f;
                if (k<F)        v=Wi[(size_t)j*F+k];
                else if (k-F<H) v=Wh[(size_t)j*H+(k-F)];
                f[e]=(f16)(v*scl[qq]);
            }
            Bf[qq][s]=f;
        }
    }
    float bq[2];
#pragma unroll
    for (int qq=0;qq<2;++qq)
        bq[qq]=(bi[96*(qsel+2*qq)+u]+bh[96*(qsel+2*qq)+u])*scl[qq];

    float c4[4]={0.f,0.f,0.f,0.f};           // B-waves only: c for rows 4g4+r

    // strip role pointers — all collapse to +tid on the block-private strip
    unsigned*       ysst = (unsigned*)strip + tid;           // store slot t=0
    const unsigned* yld  = (const unsigned*)strip + (ST_T/2) + tid;  // load t=1
    const int yr=(tid*2)/H, yk=(tid*2)-yr*H;
    const int yoff = yr*KPB + ((yk*2)^((yr&7)<<4));

    const int xr=tid/24, xk=tid-xr*24;
    const bool xact = IS_L0 && (tid < NB*24);
    const float* xbase = xact ? x32 + (size_t)(row0+xr)*(T_STEPS*24) + xk : nullptr;
    const int xoff = xr*KPB + ((xk*2)^((xr&7)<<4));

    // stage t=0 into buffer 0
    if constexpr (IS_L0){
        if (xact){
            float v=xbase[0];
            f16 vh=(f16)v, vl=(f16)(v-(float)vh);
            *(f16*)((char*)sh+xoff)=vh; *(f16*)((char*)sl+xoff)=vl;
        }
    } else {
        unsigned v = *((const unsigned*)strip + tid);
        *(unsigned*)((char*)sh+yoff)=v;
    }
    __syncthreads();

    // 2-deep prefetch prologue: yvA <- strip[1]
    unsigned yvA=0u;
    if constexpr (!IS_L0){ yvA = *yld; yld += ST_T/2; }

    const int aswz=(j15&7)<<4;
    const int abase=j15*KPB;
    // p exchange: lane-aligned, p_lds[(g*64+lane)*4 + r] f32
    const int pbase = (g*64+lane)*16;        // bytes
    // B h-write offsets (row=4g4+r)
    int nhoB[4], hsiB[4];
#pragma unroll
    for (int r=0;r<4;++r){
        int row=4*g4+r;
        nhoB[r]=row*KPB + (((F+u)*2)^((row&7)<<4));
        hsiB[r]=row*96+u;
    }

#pragma unroll 1
    for (int t=0;t<T_STEPS;++t){
        const int cur=t&1, nxt=cur^1;
        const char* chb=(const char*)(sh+cur*BUF);
        const char* clb=HAS_LO ? (const char*)(sl+cur*BUF) : nullptr;
        char*       nhb=(char*)(sh+nxt*BUF);
        char*       nlb=HAS_LO ? (char*)(sl+nxt*BUF) : nullptr;

        float xv=0.f; unsigned yvB=0u;
        if constexpr (IS_L0){
            if (xact && t+1<T_STEPS) xv = xbase[(size_t)(t+1)*24];
        } else {
            if (t+2<T_STEPS){ yvB = *yld; yld += ST_T/2; }
        }
        __builtin_amdgcn_sched_barrier(0);

        unsigned hbits=0u;
        if (HAS_YSOUT && t>0) hbits = *(const unsigned*)(chb + ysrd_off);

        // ---- MFMA phase: 2 gates x parity-split chains ----
        f32x4 acc[2][2];
#pragma unroll
        for (int qq=0;qq<2;++qq){
            f32x4 a={bq[qq],bq[qq],bq[qq],bq[qq]}; acc[qq][0]=a;
            f32x4 z={0.f,0.f,0.f,0.f};              acc[qq][1]=z;
        }
#pragma unroll
        for (int s=0;s<KS;++s){
            int kb=((s*64+g4*16)^aswz);
            f16x8 ah=*(const f16x8*)(chb+abase+kb);
            if (s&1){
                acc[0][1]=__builtin_amdgcn_mfma_f32_16x16x32_f16(ah,Bf[0][s],acc[0][1],0,0,0);
                acc[1][1]=__builtin_amdgcn_mfma_f32_16x16x32_f16(ah,Bf[1][s],acc[1][1],0,0,0);
            } else {
                acc[0][0]=__builtin_amdgcn_mfma_f32_16x16x32_f16(ah,Bf[0][s],acc[0][0],0,0,0);
                acc[1][0]=__builtin_amdgcn_mfma_f32_16x16x32_f16(ah,Bf[1][s],acc[1][0],0,0,0);
            }
        }
        if constexpr (HAS_LO){
            int kb=((g4*16)^aswz);
            f16x8 al=*(const f16x8*)(clb+abase+kb);
            acc[0][1]=__builtin_amdgcn_mfma_f32_16x16x32_f16(al,Bf[0][0],acc[0][1],0,0,0);
            acc[1][1]=__builtin_amdgcn_mfma_f32_16x16x32_f16(al,Bf[1][0],acc[1][1],0,0,0);
        }

        // pre-barrier activation (wave-uniform branch on qsel)
        float af[4], ao[4];
        if (qsel==0){
            // A: p = sig(i)*tanh(g) -> p_lds (2x b64, lane-aligned)
#pragma unroll
            for (int pr=0;pr<2;++pr){
                float i0=sig2(acc[0][0][2*pr  ]+acc[0][1][2*pr  ]);
                float i1=sig2(acc[0][0][2*pr+1]+acc[0][1][2*pr+1]);
                float g0=tanh2(acc[1][0][2*pr  ]+acc[1][1][2*pr  ]);
                float g1=tanh2(acc[1][0][2*pr+1]+acc[1][1][2*pr+1]);
                f32x2 p={i0*g0, i1*g1};
                *(f32x2*)((char*)p_lds + pbase + pr*8) = p;
            }
        } else {
            // B: pre-activate f,o (off the post-barrier chain)
#pragma unroll
            for (int r=0;r<4;++r){
                af[r]=sig2(acc[0][0][r]+acc[0][1][r]);
                ao[r]=sig2(acc[1][0][r]+acc[1][1][r]);
            }
        }
        lds_barrier();   // p visible; hbits drained

        if (HAS_YSOUT && t>0){ *ysst = hbits; ysst += ST_T/2; }

        // ---- B-waves: register-resident cell update + h write ----
        if (qsel==1){
            f32x2 pA = *(const f32x2*)((const char*)p_lds + pbase);
            f32x2 pB = *(const f32x2*)((const char*)p_lds + pbase + 8);
            float p4[4]={pA[0],pA[1],pB[0],pB[1]};
#pragma unroll
            for (int r=0;r<4;++r){
                float c = af[r]*c4[r] + p4[r];
                c4[r]=c;
                float h = ao[r]*tanh_c(c);
                *(f16*)(nhb + nhoB[r]) = (f16)h;
                if constexpr (WRITE_HSUM){ if (t==T_STEPS-1) hsum[hsiB[r]]=h; }
                if constexpr (ADD_HSUM)  { if (t==T_STEPS-1) hsum[hsiB[r]]+=h; }
            }
        }
        // staged input -> buf[nxt] (all threads)
        if (t+1<T_STEPS){
            if constexpr (IS_L0){
                if (xact){
                    f16 vh=(f16)xv, vl=(f16)(xv-(float)vh);
                    *(f16*)(nhb+xoff)=vh; *(f16*)(nlb+xoff)=vl;
                }
            } else {
                *(unsigned*)(nhb+yoff)=yvA;
            }
        }
        lds_barrier();   // h + staged input visible for next step
        yvA = yvB;
    }
    // final strip store: h(T-1) sits in buf[0] (T even)
    if constexpr (HAS_YSOUT){
        unsigned hbits = *(const unsigned*)((const char*)sh + ysrd_off);
        asm volatile("s_waitcnt lgkmcnt(0)" ::: "memory");
        *ysst = hbits;
    }
}

__global__ __launch_bounds__(NTH, 1)
void lstm_all(const float* __restrict__ x,
              const float* __restrict__ W_ih0,
              const float* __restrict__ W_ih_rest,
              const float* __restrict__ W_hh,
              const float* __restrict__ b_ih,
              const float* __restrict__ b_hh,
              const float* __restrict__ fc1_w, const float* __restrict__ fc1_b,
              const float* __restrict__ fc2_w, const float* __restrict__ fc2_b,
              const float* __restrict__ fc3_w, const float* __restrict__ fc3_b,
              f16* __restrict__ ws_strip, float* __restrict__ out)
{
    __shared__ f16 sh[2*16*192];           // act hi (max KP=192), double-buffered
    __shared__ f16 sl[2*16*128];           // act lo (L0 only, KP=128)
    __shared__ float p_lds[6*64*4];        // A->B product exchange, lane-aligned
    __shared__ float hsum[16*96];
    __shared__ float z1[16*16];
    __shared__ float z2[16*8];

    const int tid=threadIdx.x;
    const int b=blockIdx.x, row0=b*NB;
    f16* strip = ws_strip + (size_t)b*T_STEPS*ST_T;
    const int GH = 384*96;

    layer_run<24, true,  true,  false, false>(x, strip, W_ih0,             W_hh,        b_ih,          b_hh,          sh,sl,p_lds,hsum,row0);
    __syncthreads();
    layer_run<96, false, true,  true,  false>(nullptr, strip, W_ih_rest,        W_hh+1*GH, b_ih+1*384, b_hh+1*384, sh,sl,p_lds,hsum,row0);
    __syncthreads();
    layer_run<96, false, true,  false, false>(nullptr, strip, W_ih_rest+1*GH, W_hh+2*GH, b_ih+2*384, b_hh+2*384, sh,sl,p_lds,hsum,row0);
    __syncthreads();
    layer_run<96, false, false, false, true >(nullptr, strip, W_ih_rest+2*GH, W_hh+3*GH, b_ih+3*384, b_hh+3*384, sh,sl,p_lds,hsum,row0);
    __syncthreads();

    // ---- fused head: relu(hsum) -> fc1 -> relu -> fc2 -> relu -> fc3 ----
    if (tid<256){
        int r=tid>>4, jj=tid&15;
        float a=fc1_b[jj];
        for (int uu=0;uu<96;++uu) a+=fc1_w[jj*96+uu]*fmaxf(hsum[r*96+uu],0.f);
        z1[r*16+jj]=fmaxf(a,0.f);
    }
    __syncthreads();
    if (tid<128){
        int r=tid>>3, jj=tid&7;
        float a=fc2_b[jj];
#pragma unroll
        for (int uu=0;uu<16;++uu) a+=fc2_w[jj*16+uu]*z1[r*16+uu];
        z2[r*8+jj]=fmaxf(a,0.f);
    }
    __syncthreads();
    if (tid<16){
        float a=fc3_b[0];
#pragma unroll
        for (int uu=0;uu<8;++uu) a+=fc3_w[uu]*z2[tid*8+uu];
        out[row0+tid]=a;
    }
}

extern "C" void kernel_launch(void* const* d_in, const int* in_sizes, int n_in,
                              void* d_out, int out_size, void* d_ws, size_t ws_size,
                              hipStream_t stream) {
    const float* x         = (const float*)d_in[0];
    const float* W_ih0     = (const float*)d_in[1];
    const float* W_ih_rest = (const float*)d_in[2];
    const float* W_hh      = (const float*)d_in[3];
    const float* b_ih      = (const float*)d_in[4];
    const float* b_hh      = (const float*)d_in[5];
    const float* fc1_w     = (const float*)d_in[6];
    const float* fc1_b     = (const float*)d_in[7];
    const float* fc2_w     = (const float*)d_in[8];
    const float* fc2_b     = (const float*)d_in[9];
    const float* fc3_w     = (const float*)d_in[10];
    const float* fc3_b     = (const float*)d_in[11];
    float* out = (float*)d_out;

    const size_t WS = (size_t)NBLK * T_STEPS * ST_T * sizeof(f16);  // ~100.7 MB
    if (ws_size < WS) {
        hipMemsetAsync(d_out, 0, (size_t)out_size * sizeof(float), stream);
        return;
    }

    lstm_all<<<dim3(NBLK), dim3(NTH), 0, stream>>>(
        x, W_ih0, W_ih_rest, W_hh, b_ih, b_hh,
        fc1_w, fc1_b, fc2_w, fc2_b, fc3_w, fc3_b,
        (f16*)d_ws, out);
}

// Round 22
// 555.082 us; speedup vs baseline: 1.5545x; 1.0116x over previous
//
#include <hip/hip_runtime.h>
#include <math.h>

typedef _Float16 f16;
typedef _Float16 f16x8 __attribute__((ext_vector_type(8)));
typedef float f32x4 __attribute__((ext_vector_type(4)));
typedef float f32x2 __attribute__((ext_vector_type(2)));

#define B_TOTAL 4096
#define T_STEPS 128
#define H 96
#define NB 16               // batch rows per block
#define NTH 768             // 12 waves = 3 waves/SIMD
#define NBLK (B_TOTAL/NB)   // 256 blocks = 1 per CU
#define ST_T (NB*H)         // f16 per strip timestep slot = 1536
#define LOG2E 1.44269504088896f

// exp2-folded nonlinearities (R19), v_rcp (R18).
__device__ __forceinline__ float sig2(float vp){   // vp = v * log2e
    return __builtin_amdgcn_rcpf(1.f + __builtin_amdgcn_exp2f(-vp));
}
__device__ __forceinline__ float tanh2(float vpp){ // vpp = v * 2log2e
    return 1.f - 2.f*__builtin_amdgcn_rcpf(__builtin_amdgcn_exp2f(vpp) + 1.f);
}
__device__ __forceinline__ float tanh_c(float c){  // c in true scale
    return tanh2(c * (2.f*LOG2E));
}

// LDS-only barrier: no vmcnt(0) drain (R13-proven safe here).
__device__ __forceinline__ void lds_barrier(){
    __builtin_amdgcn_sched_barrier(0);
    asm volatile("s_waitcnt lgkmcnt(0)" ::: "memory");
    __builtin_amdgcn_s_barrier();
    __builtin_amdgcn_sched_barrier(0);
}

// R22 (on R21's A/B gate-pairing):
//  - p exchange via ONE ds_write_b128 / ds_read_b128 per lane (16B-stride
//    canonical pattern; R21's f32x2@16B was 8-way bank-conflicted).
//  - staging, ys store, hbits re-read moved to A-waves ONLY (uint2 forms):
//    off B's post-barrier critical path, onto A's idle slot.
//  - T5 setprio(1) around B's post-barrier cell update (genuine role-split
//    schedule = T5's stated prerequisite).
template<int F, bool IS_L0, bool HAS_YSOUT, bool WRITE_HSUM, bool ADD_HSUM>
__device__ __forceinline__ void layer_run(
    const float* __restrict__ x32, f16* __restrict__ strip,
    const float* __restrict__ Wi, const float* __restrict__ Wh,
    const float* __restrict__ bi, const float* __restrict__ bh,
    f16* sh, f16* sl, float* p_lds, float* hsum, int row0)
{
    constexpr int  KS   = (F + H + 31)/32;   // 4 (F=24) or 6 (F=96)
    constexpr int  KP   = KS*32;
    constexpr int  KPB  = KP*2;
    constexpr bool HAS_LO = IS_L0;
    constexpr int  BUF  = 16*KP;

    const int tid=threadIdx.x, lane=tid&63, w=tid>>6;
    const int j15=lane&15, g4=lane>>4;
    const int g=w>>1;                        // unit group 0..5
    const int qsel=w&1;                      // 0: A={i,g}; 1: B={f,o}
    const int u=16*g+j15;
    const int aidx=(w>>1)*64+lane;           // A-thread index 0..383 (w even)

    // A-wave roles (uint2 = 4 consecutive halves of one row)
    const int srow=aidx/24, sk0=(aidx-srow*24)*4;
    const int sswz=(srow&7)<<4;
    const int ysrd_off = srow*KPB + (((F+sk0)*2) ^ sswz);  // h region (read)
    const int yoffA    = srow*KPB + (((sk0)*2) ^ sswz);    // input region (write)

    for (int i=tid;i<2*BUF;i+=NTH) sh[i]=(f16)0.f;
    if constexpr (HAS_LO)
        for (int i=tid;i<2*BUF;i+=NTH) sl[i]=(f16)0.f;

    // weight B-frags, PRE-SCALED. A -> gates {0 (i), 2 (g)}, B -> {1 (f), 3 (o)}
    f16x8 Bf[2][KS];
    float scl[2];
#pragma unroll
    for (int qq=0;qq<2;++qq){
        int qg = qsel + 2*qq;
        scl[qq] = (qg==2) ? 2.f*LOG2E : LOG2E;
    }
#pragma unroll
    for (int qq=0;qq<2;++qq){
        const int j=96*(qsel+2*qq)+u;
#pragma unroll
        for (int s=0;s<KS;++s){
            f16x8 f;
#pragma unroll
            for (int e=0;e<8;++e){
                int k=32*s+8*g4+e;
                float v=0.f;
                if (k<F)        v=Wi[(size_t)j*F+k];
                else if (k-F<H) v=Wh[(size_t)j*H+(k-F)];
                f[e]=(f16)(v*scl[qq]);
            }
            Bf[qq][s]=f;
        }
    }
    float bq[2];
#pragma unroll
    for (int qq=0;qq<2;++qq)
        bq[qq]=(bi[96*(qsel+2*qq)+u]+bh[96*(qsel+2*qq)+u])*scl[qq];

    float c4[4]={0.f,0.f,0.f,0.f};           // B-waves: register-resident c

    // A-wave strip pointers (uint2 granularity)
    uint2*       ysst2 = (uint2*)strip + aidx;                 // store slot t=0
    const uint2* yld2  = (const uint2*)strip + (ST_T/4) + aidx; // load t=1

    const int xr=aidx/24, xk=aidx-xr*24;     // IS_L0: A-threads stage x
    const bool xact = IS_L0 && (qsel==0);
    const float* xbase = xact ? x32 + (size_t)(row0+xr)*(T_STEPS*24) + xk : nullptr;
    const int xoff = xr*KPB + ((xk*2)^((xr&7)<<4));

    // stage t=0 into buffer 0 (A-waves)
    if (qsel==0){
        if constexpr (IS_L0){
            float v=xbase[0];
            f16 vh=(f16)v, vl=(f16)(v-(float)vh);
            *(f16*)((char*)sh+xoff)=vh; *(f16*)((char*)sl+xoff)=vl;
        } else {
            uint2 v = *((const uint2*)strip + aidx);
            *(uint2*)((char*)sh+yoffA)=v;
        }
    }
    __syncthreads();

    // 2-deep prefetch prologue (A-waves): yvA2 <- strip[1]
    uint2 yvA2={0u,0u};
    if (!IS_L0 && qsel==0){ yvA2 = *yld2; yld2 += ST_T/4; }

    const int aswz=(j15&7)<<4;
    const int abase=j15*KPB;
    const int pbase=(g*64+lane)*16;          // p exchange, 16B/lane (b128)
    int nhoB[4], hsiB[4];
#pragma unroll
    for (int r=0;r<4;++r){
        int row=4*g4+r;
        nhoB[r]=row*KPB + (((F+u)*2)^((row&7)<<4));
        hsiB[r]=row*96+u;
    }

#pragma unroll 1
    for (int t=0;t<T_STEPS;++t){
        const int cur=t&1, nxt=cur^1;
        const char* chb=(const char*)(sh+cur*BUF);
        const char* clb=HAS_LO ? (const char*)(sl+cur*BUF) : nullptr;
        char*       nhb=(char*)(sh+nxt*BUF);
        char*       nlb=HAS_LO ? (char*)(sl+nxt*BUF) : nullptr;

        float xv=0.f; uint2 yvB2={0u,0u};
        if constexpr (IS_L0){
            if (xact && t+1<T_STEPS) xv = xbase[(size_t)(t+1)*24];
        } else {
            if (qsel==0 && t+2<T_STEPS){ yvB2 = *yld2; yld2 += ST_T/4; }
        }
        __builtin_amdgcn_sched_barrier(0);

        // A-waves: re-read h(t-1) uint2 from buf[cur] for the delayed ys store
        uint2 hbits2={0u,0u};
        if (HAS_YSOUT && qsel==0 && t>0)
            hbits2 = *(const uint2*)(chb + ysrd_off);

        // ---- MFMA phase: 2 gates x parity-split chains ----
        f32x4 acc[2][2];
#pragma unroll
        for (int qq=0;qq<2;++qq){
            f32x4 a={bq[qq],bq[qq],bq[qq],bq[qq]}; acc[qq][0]=a;
            f32x4 z={0.f,0.f,0.f,0.f};              acc[qq][1]=z;
        }
#pragma unroll
        for (int s=0;s<KS;++s){
            int kb=((s*64+g4*16)^aswz);
            f16x8 ah=*(const f16x8*)(chb+abase+kb);
            if (s&1){
                acc[0][1]=__builtin_amdgcn_mfma_f32_16x16x32_f16(ah,Bf[0][s],acc[0][1],0,0,0);
                acc[1][1]=__builtin_amdgcn_mfma_f32_16x16x32_f16(ah,Bf[1][s],acc[1][1],0,0,0);
            } else {
                acc[0][0]=__builtin_amdgcn_mfma_f32_16x16x32_f16(ah,Bf[0][s],acc[0][0],0,0,0);
                acc[1][0]=__builtin_amdgcn_mfma_f32_16x16x32_f16(ah,Bf[1][s],acc[1][0],0,0,0);
            }
        }
        if constexpr (HAS_LO){
            int kb=((g4*16)^aswz);
            f16x8 al=*(const f16x8*)(clb+abase+kb);
            acc[0][1]=__builtin_amdgcn_mfma_f32_16x16x32_f16(al,Bf[0][0],acc[0][1],0,0,0);
            acc[1][1]=__builtin_amdgcn_mfma_f32_16x16x32_f16(al,Bf[1][0],acc[1][1],0,0,0);
        }

        // pre-barrier activation (wave-uniform branch on qsel)
        float af[4], ao[4];
        if (qsel==0){
            // A: p = sig(i)*tanh(g), ONE b128 write (conflict-free 16B stride)
            f32x4 p4;
#pragma unroll
            for (int r=0;r<4;++r){
                float iv=sig2(acc[0][0][r]+acc[0][1][r]);
                float gv=tanh2(acc[1][0][r]+acc[1][1][r]);
                p4[r]=iv*gv;
            }
            *(f32x4*)((char*)p_lds + pbase) = p4;
        } else {
            // B: pre-activate f,o (off the post-barrier chain)
#pragma unroll
            for (int r=0;r<4;++r){
                af[r]=sig2(acc[0][0][r]+acc[0][1][r]);
                ao[r]=sig2(acc[1][0][r]+acc[1][1][r]);
            }
        }
        lds_barrier();   // p visible; hbits drained

        if (qsel==1){
            // ---- B critical path: register-resident cell update + h write ----
            __builtin_amdgcn_s_setprio(1);
            f32x4 p4 = *(const f32x4*)((const char*)p_lds + pbase);
#pragma unroll
            for (int r=0;r<4;++r){
                float c = af[r]*c4[r] + p4[r];
                c4[r]=c;
                float h = ao[r]*tanh_c(c);
                *(f16*)(nhb + nhoB[r]) = (f16)h;
                if constexpr (WRITE_HSUM){ if (t==T_STEPS-1) hsum[hsiB[r]]=h; }
                if constexpr (ADD_HSUM)  { if (t==T_STEPS-1) hsum[hsiB[r]]+=h; }
            }
            __builtin_amdgcn_s_setprio(0);
        } else {
            // ---- A idle slot: ys store + staging (off B's path) ----
            if (HAS_YSOUT && t>0){ *ysst2 = hbits2; ysst2 += ST_T/4; }
            if (t+1<T_STEPS){
                if constexpr (IS_L0){
                    f16 vh=(f16)xv, vl=(f16)(xv-(float)vh);
                    *(f16*)(nhb+xoff)=vh; *(f16*)(nlb+xoff)=vl;
                } else {
                    *(uint2*)(nhb+yoffA)=yvA2;
                }
            }
        }
        lds_barrier();   // h + staged input visible for next step
        yvA2 = yvB2;
    }
    // final ys store: h(T-1) sits in buf[0] (T even); A-waves
    if (HAS_YSOUT && qsel==0){
        uint2 hb = *(const uint2*)((const char*)sh + ysrd_off);
        asm volatile("s_waitcnt lgkmcnt(0)" ::: "memory");
        *ysst2 = hb;
    }
}

__global__ __launch_bounds__(NTH, 1)
void lstm_all(const float* __restrict__ x,
              const float* __restrict__ W_ih0,
              const float* __restrict__ W_ih_rest,
              const float* __restrict__ W_hh,
              const float* __restrict__ b_ih,
              const float* __restrict__ b_hh,
              const float* __restrict__ fc1_w, const float* __restrict__ fc1_b,
              const float* __restrict__ fc2_w, const float* __restrict__ fc2_b,
              const float* __restrict__ fc3_w, const float* __restrict__ fc3_b,
              f16* __restrict__ ws_strip, float* __restrict__ out)
{
    __shared__ f16 sh[2*16*192];           // act hi (max KP=192), double-buffered
    __shared__ f16 sl[2*16*128];           // act lo (L0 only, KP=128)
    __shared__ float p_lds[6*64*4];        // A->B product exchange, 16B/lane
    __shared__ float hsum[16*96];
    __shared__ float z1[16*16];
    __shared__ float z2[16*8];

    const int tid=threadIdx.x;
    const int b=blockIdx.x, row0=b*NB;
    f16* strip = ws_strip + (size_t)b*T_STEPS*ST_T;
    const int GH = 384*96;

    layer_run<24, true,  true,  false, false>(x, strip, W_ih0,             W_hh,        b_ih,          b_hh,          sh,sl,p_lds,hsum,row0);
    __syncthreads();
    layer_run<96, false, true,  true,  false>(nullptr, strip, W_ih_rest,        W_hh+1*GH, b_ih+1*384, b_hh+1*384, sh,sl,p_lds,hsum,row0);
    __syncthreads();
    layer_run<96, false, true,  false, false>(nullptr, strip, W_ih_rest+1*GH, W_hh+2*GH, b_ih+2*384, b_hh+2*384, sh,sl,p_lds,hsum,row0);
    __syncthreads();
    layer_run<96, false, false, false, true >(nullptr, strip, W_ih_rest+2*GH, W_hh+3*GH, b_ih+3*384, b_hh+3*384, sh,sl,p_lds,hsum,row0);
    __syncthreads();

    // ---- fused head: relu(hsum) -> fc1 -> relu -> fc2 -> relu -> fc3 ----
    if (tid<256){
        int r=tid>>4, jj=tid&15;
        float a=fc1_b[jj];
        for (int uu=0;uu<96;++uu) a+=fc1_w[jj*96+uu]*fmaxf(hsum[r*96+uu],0.f);
        z1[r*16+jj]=fmaxf(a,0.f);
    }
    __syncthreads();
    if (tid<128){
        int r=tid>>3, jj=tid&7;
        float a=fc2_b[jj];
#pragma unroll
        for (int uu=0;uu<16;++uu) a+=fc2_w[jj*16+uu]*z1[r*16+uu];
        z2[r*8+jj]=fmaxf(a,0.f);
    }
    __syncthreads();
    if (tid<16){
        float a=fc3_b[0];
#pragma unroll
        for (int uu=0;uu<8;++uu) a+=fc3_w[uu]*z2[tid*8+uu];
        out[row0+tid]=a;
    }
}

extern "C" void kernel_launch(void* const* d_in, const int* in_sizes, int n_in,
                              void* d_out, int out_size, void* d_ws, size_t ws_size,
                              hipStream_t stream) {
    const float* x         = (const float*)d_in[0];
    const float* W_ih0     = (const float*)d_in[1];
    const float* W_ih_rest = (const float*)d_in[2];
    const float* W_hh      = (const float*)d_in[3];
    const float* b_ih      = (const float*)d_in[4];
    const float* b_hh      = (const float*)d_in[5];
    const float* fc1_w     = (const float*)d_in[6];
    const float* fc1_b     = (const float*)d_in[7];
    const float* fc2_w     = (const float*)d_in[8];
    const float* fc2_b     = (const float*)d_in[9];
    const float* fc3_w     = (const float*)d_in[10];
    const float* fc3_b     = (const float*)d_in[11];
    float* out = (float*)d_out;

    const size_t WS = (size_t)NBLK * T_STEPS * ST_T * sizeof(f16);  // ~100.7 MB
    if (ws_size < WS) {
        hipMemsetAsync(d_out, 0, (size_t)out_size * sizeof(float), stream);
        return;
    }

    lstm_all<<<dim3(NBLK), dim3(NTH), 0, stream>>>(
        x, W_ih0, W_ih_rest, W_hh, b_ih, b_hh,
        fc1_w, fc1_b, fc2_w, fc2_b, fc3_w, fc3_b,
        (f16*)d_ws, out);
}